// Round 1
// baseline (6455.609 us; speedup 1.0000x reference)
//
#include <hip/hip_runtime.h>

#define NN 8
#define CC 256
#define HWL 9216
#define HEADS 8
#define DIM 32
#define CNTF 73728.0f

// ws float-index layout
#define WS_DENOM 1024          // 2048 floats  [n*8+h][k]
#define WS_CTX   3072          // 65536 floats [n][h][k][v]
// byte offsets for bf16 buffers
#define WS_KEYS_BYTES 274432u                       // 8*256*9216 bf16
#define WS_VALS_BYTES (274432u + 37748736u)

__device__ __forceinline__ float plo(unsigned u){ return __uint_as_float(u << 16); }
__device__ __forceinline__ float phi(unsigned u){ return __uint_as_float(u & 0xFFFF0000u); }
__device__ __forceinline__ unsigned f2bf(float f){
  unsigned u = __float_as_uint(f);
  return (u + 0x7FFFu + ((u >> 16) & 1u)) >> 16;   // RNE bf16 (finite inputs)
}
__device__ __forceinline__ unsigned pack2(float lo, float hi){
  return f2bf(lo) | (f2bf(hi) << 16);
}

// ---------------- init: zero denom + ctx accumulators (re-done every launch) ----
__global__ __launch_bounds__(256) void k_init(float* __restrict__ ws){
  int i = blockIdx.x * 256 + threadIdx.x;
  if (i < 67584) ws[WS_DENOM + i] = 0.0f;
}

// ---------------- per-channel BN stats (sum, sumsq) ----------------------------
__global__ __launch_bounds__(256) void k_stats(const float* __restrict__ q,
                                               const float* __restrict__ kv,
                                               float* __restrict__ ws){
  int b = blockIdx.x, t = threadIdx.x;
  const float* x = (b < 256) ? q : kv;
  int c = b & 255;
  float s = 0.f, ss = 0.f;
  const float* base = x + (size_t)c * HWL;
  for (int n = 0; n < NN; ++n){
    const float* p = base + (size_t)n * CC * HWL;
    for (int j = t; j < HWL; j += 256){ float v = p[j]; s += v; ss += v*v; }
  }
  __shared__ float red[2][256];
  red[0][t] = s; red[1][t] = ss; __syncthreads();
  for (int off = 128; off > 0; off >>= 1){
    if (t < off){ red[0][t] += red[0][t+off]; red[1][t] += red[1][t+off]; }
    __syncthreads();
  }
  if (t == 0){
    int base_off = (b < 256) ? 0 : 512;
    ws[base_off + c]       = red[0][0];
    ws[base_off + 256 + c] = red[1][0];
  }
}

// ---------------- stage BN'd input tile as packed bf16 pairs into LDS ----------
__device__ __forceinline__ void stage_x(const float* __restrict__ x,
    const float* __restrict__ ws, int statOff,
    const float* __restrict__ gamma, const float* __restrict__ beta,
    int n, int l0, int t, unsigned (*xpk)[64])
{
  for (int j = 0; j < 8; ++j){
    int i4 = j*256 + t;
    int c2 = i4 >> 4;
    int p4 = (i4 & 15) << 2;
    int c  = c2 << 1;
    float s0 = ws[statOff + c],     q0 = ws[statOff + 256 + c];
    float s1 = ws[statOff + c + 1], q1 = ws[statOff + 256 + c + 1];
    float m0 = s0 * (1.0f/CNTF), m1 = s1 * (1.0f/CNTF);
    float v0 = q0 * (1.0f/CNTF) - m0*m0, v1 = q1 * (1.0f/CNTF) - m1*m1;
    float r0 = rsqrtf(v0 + 1e-3f), r1 = rsqrtf(v1 + 1e-3f);
    float sc0 = r0 * gamma[c],   sh0 = beta[c]   - m0*sc0;
    float sc1 = r1 * gamma[c+1], sh1 = beta[c+1] - m1*sc1;
    const float* src = x + ((size_t)n*CC + c)*HWL + l0 + p4;
    float4 a = *(const float4*)src;
    float4 b = *(const float4*)(src + HWL);
    uint4 u;
    u.x = pack2(fmaf(a.x, sc0, sh0), fmaf(b.x, sc1, sh1));
    u.y = pack2(fmaf(a.y, sc0, sh0), fmaf(b.y, sc1, sh1));
    u.z = pack2(fmaf(a.z, sc0, sh0), fmaf(b.z, sc1, sh1));
    u.w = pack2(fmaf(a.w, sc0, sh0), fmaf(b.w, sc1, sh1));
    *(uint4*)&xpk[c2][p4] = u;
  }
}

// ---------------- 2-row × 256-K dot against packed LDS tile --------------------
__device__ __forceinline__ void gemm2rows(const unsigned (*X)[64],
    const float* __restrict__ W0row, const float* __restrict__ W1row,
    int p, float& r0, float& r1)
{
  const float4* W0 = (const float4*)W0row;
  const float4* W1 = (const float4*)W1row;
  float a0=0.f, b0=0.f, a1=0.f, b1=0.f;
  #pragma unroll
  for (int c4 = 0; c4 < 64; c4 += 2){
    float4 w0  = W0[c4],   w1  = W1[c4];
    float4 w0b = W0[c4+1], w1b = W1[c4+1];
    unsigned u0 = X[2*c4][p],   u1 = X[2*c4+1][p];
    unsigned u2 = X[2*c4+2][p], u3 = X[2*c4+3][p];
    float x0 = plo(u0), x1 = phi(u0), x2 = plo(u1), x3 = phi(u1);
    float x4 = plo(u2), x5 = phi(u2), x6 = plo(u3), x7 = phi(u3);
    a0 = fmaf(w0.x, x0, a0);  a0 = fmaf(w0.y, x1, a0);
    a0 = fmaf(w0.z, x2, a0);  a0 = fmaf(w0.w, x3, a0);
    b0 = fmaf(w0b.x, x4, b0); b0 = fmaf(w0b.y, x5, b0);
    b0 = fmaf(w0b.z, x6, b0); b0 = fmaf(w0b.w, x7, b0);
    a1 = fmaf(w1.x, x0, a1);  a1 = fmaf(w1.y, x1, a1);
    a1 = fmaf(w1.z, x2, a1);  a1 = fmaf(w1.w, x3, a1);
    b1 = fmaf(w1b.x, x4, b1); b1 = fmaf(w1b.y, x5, b1);
    b1 = fmaf(w1b.z, x6, b1); b1 = fmaf(w1b.w, x7, b1);
  }
  r0 = a0 + b0; r1 = a1 + b1;
}

// ---------------- K/V projection: keys,values (bf16) to ws ---------------------
__global__ __launch_bounds__(256) void k_proj_kv(const float* __restrict__ kv,
    const float* __restrict__ Wk, const float* __restrict__ Wv,
    const float* __restrict__ gamma, const float* __restrict__ beta,
    float* __restrict__ ws)
{
  __shared__ unsigned xpk[128][64];
  int t = threadIdx.x, bx = blockIdx.x;
  int n = bx / 144, lb = bx % 144;
  int l0 = lb * 64;
  stage_x(kv, ws, 512, gamma, beta, n, l0, t, xpk);
  __syncthreads();
  int p = t & 63, og = t >> 6;              // og in 0..3, 128 rows each
  unsigned short* keys = (unsigned short*)((char*)ws + WS_KEYS_BYTES);
  unsigned short* vals = (unsigned short*)((char*)ws + WS_VALS_BYTES);
  for (int m = 0; m < 64; ++m){
    int o0 = og*128 + 2*m;                  // 0..510 (pairs never cross 256)
    const float* W0 = (o0 < 256) ? (Wk + (size_t)o0*CC) : (Wv + (size_t)(o0-256)*CC);
    float r0, r1;
    gemm2rows(xpk, W0, W0 + CC, p, r0, r1);
    int orow = o0 & 255;
    size_t gi = ((size_t)n*CC + orow)*HWL + l0 + p;
    unsigned short v0 = (unsigned short)f2bf(r0);
    unsigned short v1 = (unsigned short)f2bf(r1);
    if (o0 < 256){ keys[gi] = v0; keys[gi + HWL] = v1; }
    else         { vals[gi] = v0; vals[gi + HWL] = v1; }
  }
}

// ---------------- context accumulation (no max subtraction needed) -------------
__global__ __launch_bounds__(256) void k_ctx(float* __restrict__ ws)
{
  __shared__ float eb[32][257];
  __shared__ float vb[32][257];
  int t = threadIdx.x, bx = blockIdx.x;
  int nh = bx / 36, ch = bx % 36;
  int n = nh >> 3, h = nh & 7;
  int l0 = ch * 256;
  const unsigned short* keys = (const unsigned short*)((const char*)ws + WS_KEYS_BYTES);
  const unsigned short* vals = (const unsigned short*)((const char*)ws + WS_VALS_BYTES);
  for (int j = 0; j < 32; ++j){
    size_t gi = ((size_t)n*CC + h*DIM + j)*HWL + l0 + t;
    eb[j][t] = __expf(__uint_as_float(((unsigned)keys[gi]) << 16));
    vb[j][t] = __uint_as_float(((unsigned)vals[gi]) << 16);
  }
  __syncthreads();
  int k = t >> 3, vg = t & 7;
  float d0 = 0.f, c0 = 0.f, c1 = 0.f, c2 = 0.f, c3 = 0.f;
  #pragma unroll 4
  for (int p = 0; p < 256; ++p){
    float e = eb[k][p];
    d0 += e;
    c0 = fmaf(e, vb[vg*4+0][p], c0);
    c1 = fmaf(e, vb[vg*4+1][p], c1);
    c2 = fmaf(e, vb[vg*4+2][p], c2);
    c3 = fmaf(e, vb[vg*4+3][p], c3);
  }
  float* ctx = ws + WS_CTX + (size_t)nh*1024 + k*32 + vg*4;
  atomicAdd(ctx+0, c0); atomicAdd(ctx+1, c1);
  atomicAdd(ctx+2, c2); atomicAdd(ctx+3, c3);
  if (vg == 0) atomicAdd(ws + WS_DENOM + nh*32 + k, d0);
}

// ---------------- fused back half: Q proj + softmax + attend + reproj + res ----
__global__ __launch_bounds__(256) void k_fused(const float* __restrict__ x,
    const float* __restrict__ Wq, const float* __restrict__ Wp,
    const float* __restrict__ gamma, const float* __restrict__ beta,
    const float* __restrict__ ws, float* __restrict__ out)
{
  __shared__ unsigned xpk[128][64];   // BN'd q tile; reused as aggregated tile
  __shared__ unsigned qpk[128][64];   // packed queries
  __shared__ unsigned ctxp[8*32*16];  // normalized context, packed bf16 pairs
  int t = threadIdx.x, bx = blockIdx.x;
  int n = bx / 144, lb = bx % 144;
  int l0 = lb * 64;

  // stage normalized context (8 heads x 32 x 32)
  for (int j = 0; j < 16; ++j){
    int i  = j*256 + t;              // 0..4095
    int hk = i >> 4;                 // h*32 + k
    int v2 = (i & 15) << 1;
    float inv = 1.0f / ws[WS_DENOM + n*256 + hk];
    const float* ca = ws + WS_CTX + (size_t)n*8192 + hk*32 + v2;
    ctxp[i] = pack2(ca[0]*inv, ca[1]*inv);
  }
  stage_x(x, ws, 0, gamma, beta, n, l0, t, xpk);
  __syncthreads();

  int p = t & 63, og = t >> 6;
  // phase 1: queries = Wq @ qn  (rows og*64 .. og*64+63, pairs)
  for (int m = 0; m < 32; ++m){
    int o0 = og*64 + 2*m;
    const float* W0 = Wq + (size_t)o0*CC;
    float r0, r1;
    gemm2rows(xpk, W0, W0 + CC, p, r0, r1);
    qpk[og*32 + m][p] = pack2(r0, r1);
  }
  __syncthreads();

  // phase 2: per-(h,p) softmax over 32 + attended; write agg into xpk
  for (int task = 0; task < 2; ++task){
    int tau = t + task*256;
    int pp = tau & 63, h = tau >> 6;
    float q[32];
    #pragma unroll
    for (int j = 0; j < 16; ++j){
      unsigned u = qpk[h*16 + j][pp];
      q[2*j] = plo(u); q[2*j+1] = phi(u);
    }
    float s = 0.f;
    #pragma unroll
    for (int k2 = 0; k2 < 32; ++k2){ q[k2] = __expf(q[k2]); s += q[k2]; }
    float inv = 1.0f / s;
    float att[32];
    #pragma unroll
    for (int v = 0; v < 32; ++v) att[v] = 0.f;
    #pragma unroll
    for (int k2 = 0; k2 < 32; ++k2){
      float e = q[k2] * inv;
      const unsigned* cr = &ctxp[(h*32 + k2)*16];
      #pragma unroll
      for (int j = 0; j < 16; ++j){
        unsigned u = cr[j];
        att[2*j]   = fmaf(e, plo(u), att[2*j]);
        att[2*j+1] = fmaf(e, phi(u), att[2*j+1]);
      }
    }
    #pragma unroll
    for (int j = 0; j < 16; ++j)
      xpk[h*16 + j][pp] = pack2(att[2*j], att[2*j+1]);
  }
  __syncthreads();

  // phase 3: reproj = Wp @ agg + residual
  for (int m = 0; m < 32; ++m){
    int o0 = og*64 + 2*m;
    const float* W0 = Wp + (size_t)o0*CC;
    float r0, r1;
    gemm2rows(xpk, W0, W0 + CC, p, r0, r1);
    size_t gi = ((size_t)n*CC + o0)*HWL + l0 + p;
    out[gi]       = r0 + x[gi];
    out[gi + HWL] = r1 + x[gi + HWL];
  }
}

extern "C" void kernel_launch(void* const* d_in, const int* in_sizes, int n_in,
                              void* d_out, int out_size, void* d_ws, size_t ws_size,
                              hipStream_t stream)
{
  const float* q_in = (const float*)d_in[0];
  const float* kv   = (const float*)d_in[1];
  const float* Wq   = (const float*)d_in[2];
  const float* Wk   = (const float*)d_in[3];
  const float* Wv   = (const float*)d_in[4];
  const float* Wp   = (const float*)d_in[5];
  const float* qg   = (const float*)d_in[6];
  const float* qb   = (const float*)d_in[7];
  const float* kg   = (const float*)d_in[8];
  const float* kb   = (const float*)d_in[9];
  float* out = (float*)d_out;
  float* ws  = (float*)d_ws;

  hipLaunchKernelGGL(k_init,    dim3(264),  dim3(256), 0, stream, ws);
  hipLaunchKernelGGL(k_stats,   dim3(512),  dim3(256), 0, stream, q_in, kv, ws);
  hipLaunchKernelGGL(k_proj_kv, dim3(1152), dim3(256), 0, stream, kv, Wk, Wv, kg, kb, ws);
  hipLaunchKernelGGL(k_ctx,     dim3(2304), dim3(256), 0, stream, ws);
  hipLaunchKernelGGL(k_fused,   dim3(1152), dim3(256), 0, stream, q_in, Wq, Wp, qg, qb, ws, out);
}

// Round 2
// 366.066 us; speedup vs baseline: 17.6351x; 17.6351x over previous
//
#include <hip/hip_runtime.h>

#define L 9216
#define CNTF 73728.0f

// ws float-index offsets
#define F_COEF_Q 0
#define F_COEF_KV 512
#define F_DENOM 1024
#define F_CTX 3072
#define F_STATS 68608          // aliases keys block (dead before keys written)
// ws byte offsets
#define B_KVPROJ 274432u       // [512 o][8 n][9216 l] bf16 (keys rows 0-255, vals 256-511)
#define B_M2 278528u           // f32 [8 n][256 c][256 hk], aliases keys block (dead post k_ctx)
#define B_QSM 38023168u        // vals block; qsm [8 n][256 hk][9216 l] bf16 aliases it post k_ctx

typedef float floatx4 __attribute__((ext_vector_type(4)));
typedef __bf16 bf16x8 __attribute__((ext_vector_type(8)));

__device__ __forceinline__ unsigned f2bf(float f){
  unsigned u = __float_as_uint(f);
  return (u + 0x7FFFu + ((u >> 16) & 1u)) >> 16;   // RNE bf16 (finite inputs)
}
__device__ __forceinline__ unsigned pack2(float lo, float hi){
  return f2bf(lo) | (f2bf(hi) << 16);
}
__device__ __forceinline__ int swz(int r){ return (r ^ (r >> 4)) & 7; }

// ---------------- init: zero denom + ctx accumulators ----------------
__global__ __launch_bounds__(256) void k_init(float* __restrict__ ws){
  int i = blockIdx.x * 256 + threadIdx.x;
  if (i < 67584) ws[F_DENOM + i] = 0.0f;
}

// ---------------- per-channel BN stats (sum, sumsq) ------------------
__global__ __launch_bounds__(256) void k_stats(const float* __restrict__ q,
                                               const float* __restrict__ kv,
                                               float* __restrict__ ws){
  int b = blockIdx.x, t = threadIdx.x;
  const float* x = (b < 256) ? q : kv;
  int c = b & 255;
  float s = 0.f, ss = 0.f;
  const float* base = x + (size_t)c * L;
  for (int n = 0; n < 8; ++n){
    const float* p = base + (size_t)n * 256 * L;
    for (int j = t; j < L; j += 256){ float v = p[j]; s += v; ss += v*v; }
  }
  __shared__ float red[2][256];
  red[0][t] = s; red[1][t] = ss; __syncthreads();
  for (int off = 128; off > 0; off >>= 1){
    if (t < off){ red[0][t] += red[0][t+off]; red[1][t] += red[1][t+off]; }
    __syncthreads();
  }
  if (t == 0){
    int base_off = F_STATS + ((b < 256) ? 0 : 512);
    ws[base_off + c]       = red[0][0];
    ws[base_off + 256 + c] = red[1][0];
  }
}

// ---------------- BN coefficients: scale/shift per channel -----------
__global__ __launch_bounds__(256) void k_coef(float* __restrict__ ws,
    const float* __restrict__ qg, const float* __restrict__ qb,
    const float* __restrict__ kg, const float* __restrict__ kb){
  int t = blockIdx.x*256 + threadIdx.x;   // 0..511
  int ten = t >> 8, c = t & 255;
  float s  = ws[F_STATS + ten*512 + c];
  float ss = ws[F_STATS + ten*512 + 256 + c];
  float m = s * (1.0f/CNTF);
  float v = ss * (1.0f/CNTF) - m*m;
  float g  = ten ? kg[c] : qg[c];
  float be = ten ? kb[c] : qb[c];
  float sc = rsqrtf(v + 1e-3f) * g;
  ws[ten*512 + c] = sc;
  ws[ten*512 + 256 + c] = be - m*sc;
}

// ---------------- MFMA GEMM: out[o][l] = A[o][:256] x Xbn[:256][l] ---
// MODE 0: bf16 out (kvproj). MODE 1: softmax-over-32-rows epilogue, bf16 out (qsm).
// MODE 2: B is bf16 (qsm), f32 out + residual.
template<int MODE>
__global__ __launch_bounds__(256) void k_gemm(
    const float* __restrict__ A0, const float* __restrict__ A1, size_t a_nstride,
    const void* __restrict__ Bsrc, const float* __restrict__ coef,
    void* __restrict__ outp, const float* __restrict__ xres,
    int ors, int ons)
{
  __shared__ __align__(16) ushort As[128*64];
  __shared__ __align__(16) ushort Bs[128*64];
  const int t = threadIdx.x;
  const int lane = t & 63, wid = t >> 6;
  const int wr = wid >> 1, wc = wid & 1;
  const int lp = blockIdx.x, op = blockIdx.y, n = blockIdx.z;
  const int l0 = lp * 128, o0 = op * 128;

  const float* Ablock;
  if (o0 < 256) Ablock = A0 + a_nstride * (size_t)n + (size_t)o0 * 256;
  else          Ablock = A1 + (size_t)(o0 - 256) * 256;

  floatx4 acc[4][4] = {};

  const int arow = t >> 1, akh = t & 1;        // A stage: 2 threads/row
  const int cpair = t >> 3, lg = t & 7;        // B stage: k-pair, l-group

  for (int kc = 0; kc < 4; ++kc) {
    // ---- stage A: W f32 -> bf16, K-major rows, swizzled b128 writes
    {
      const float4* asrc = (const float4*)(Ablock + (size_t)arow*256 + kc*64 + akh*32);
      unsigned au[16];
      #pragma unroll
      for (int q = 0; q < 8; ++q) {
        float4 v = asrc[q];
        au[2*q]   = pack2(v.x, v.y);
        au[2*q+1] = pack2(v.z, v.w);
      }
      #pragma unroll
      for (int q = 0; q < 4; ++q) {
        int gq = (akh*4 + q) ^ swz(arow);
        *(uint4*)((char*)As + arow*128 + gq*16) =
            make_uint4(au[4*q], au[4*q+1], au[4*q+2], au[4*q+3]);
      }
    }
    // ---- stage B: X (f32+BN or bf16) -> transposed K-major, swizzled b32 writes
    {
      unsigned bu[16];
      if (MODE == 2) {
        const ushort* X = (const ushort*)Bsrc + ((size_t)n*256 + kc*64 + 2*cpair)*L + l0 + lg*16;
        uint4 ra  = *(const uint4*)X;
        uint4 ra2 = *(const uint4*)(X + 8);
        uint4 rb  = *(const uint4*)(X + L);
        uint4 rb2 = *(const uint4*)(X + L + 8);
        bu[0] = (ra.x & 0xFFFFu) | (rb.x << 16);  bu[1] = (ra.x >> 16) | (rb.x & 0xFFFF0000u);
        bu[2] = (ra.y & 0xFFFFu) | (rb.y << 16);  bu[3] = (ra.y >> 16) | (rb.y & 0xFFFF0000u);
        bu[4] = (ra.z & 0xFFFFu) | (rb.z << 16);  bu[5] = (ra.z >> 16) | (rb.z & 0xFFFF0000u);
        bu[6] = (ra.w & 0xFFFFu) | (rb.w << 16);  bu[7] = (ra.w >> 16) | (rb.w & 0xFFFF0000u);
        bu[8]  = (ra2.x & 0xFFFFu) | (rb2.x << 16); bu[9]  = (ra2.x >> 16) | (rb2.x & 0xFFFF0000u);
        bu[10] = (ra2.y & 0xFFFFu) | (rb2.y << 16); bu[11] = (ra2.y >> 16) | (rb2.y & 0xFFFF0000u);
        bu[12] = (ra2.z & 0xFFFFu) | (rb2.z << 16); bu[13] = (ra2.z >> 16) | (rb2.z & 0xFFFF0000u);
        bu[14] = (ra2.w & 0xFFFFu) | (rb2.w << 16); bu[15] = (ra2.w >> 16) | (rb2.w & 0xFFFF0000u);
      } else {
        int c = kc*64 + 2*cpair;
        float s0 = coef[c],     h0 = coef[256 + c];
        float s1 = coef[c + 1], h1 = coef[256 + c + 1];
        const float* Xa = (const float*)Bsrc + ((size_t)n*256 + c)*L + l0 + lg*16;
        const float* Xb = Xa + L;
        #pragma unroll
        for (int q = 0; q < 4; ++q) {
          float4 a = ((const float4*)Xa)[q];
          float4 b = ((const float4*)Xb)[q];
          bu[4*q+0] = pack2(fmaf(a.x,s0,h0), fmaf(b.x,s1,h1));
          bu[4*q+1] = pack2(fmaf(a.y,s0,h0), fmaf(b.y,s1,h1));
          bu[4*q+2] = pack2(fmaf(a.z,s0,h0), fmaf(b.z,s1,h1));
          bu[4*q+3] = pack2(fmaf(a.w,s0,h0), fmaf(b.w,s1,h1));
        }
      }
      #pragma unroll
      for (int j = 0; j < 16; ++j) {
        int ll = lg*16 + j;
        int gq = (cpair >> 2) ^ swz(ll);
        *(unsigned*)((char*)Bs + ll*128 + gq*16 + (cpair & 3)*4) = bu[j];
      }
    }
    __syncthreads();
    // ---- MFMA compute: wave tile 64x64
    #pragma unroll
    for (int ks = 0; ks < 2; ++ks) {
      bf16x8 af[4], bff[4];
      #pragma unroll
      for (int mf = 0; mf < 4; ++mf) {
        int row = wr*64 + mf*16 + (lane & 15);
        int gq = (ks*4 + (lane >> 4)) ^ swz(row);
        af[mf] = *(const bf16x8*)((const char*)As + row*128 + gq*16);
      }
      #pragma unroll
      for (int nf = 0; nf < 4; ++nf) {
        int ll = wc*64 + nf*16 + (lane & 15);
        int gq = (ks*4 + (lane >> 4)) ^ swz(ll);
        bff[nf] = *(const bf16x8*)((const char*)Bs + ll*128 + gq*16);
      }
      #pragma unroll
      for (int mf = 0; mf < 4; ++mf)
        #pragma unroll
        for (int nf = 0; nf < 4; ++nf)
          acc[mf][nf] = __builtin_amdgcn_mfma_f32_16x16x32_bf16(af[mf], bff[nf], acc[mf][nf], 0, 0, 0);
    }
    __syncthreads();
  }

  const int lcol = lane & 15;
  const int lrow4 = (lane >> 4) * 4;

  if (MODE == 1) {
    // softmax over the 32 rows of each head (rows hg*32..+31 of the wave tile)
    #pragma unroll
    for (int mf = 0; mf < 4; ++mf)
      #pragma unroll
      for (int nf = 0; nf < 4; ++nf)
        #pragma unroll
        for (int r = 0; r < 4; ++r)
          acc[mf][nf][r] = __expf(acc[mf][nf][r]);
    #pragma unroll
    for (int hg = 0; hg < 2; ++hg) {
      #pragma unroll
      for (int nf = 0; nf < 4; ++nf) {
        float s = 0.f;
        #pragma unroll
        for (int mh = 0; mh < 2; ++mh)
          #pragma unroll
          for (int r = 0; r < 4; ++r)
            s += acc[hg*2+mh][nf][r];
        s += __shfl_xor(s, 16);
        s += __shfl_xor(s, 32);
        float inv = 1.0f / s;
        #pragma unroll
        for (int mh = 0; mh < 2; ++mh)
          #pragma unroll
          for (int r = 0; r < 4; ++r)
            acc[hg*2+mh][nf][r] *= inv;
      }
    }
  }

  if (MODE == 2) {
    float* outf = (float*)outp;
    #pragma unroll
    for (int mf = 0; mf < 4; ++mf)
      #pragma unroll
      for (int r = 0; r < 4; ++r) {
        int orow = o0 + wr*64 + mf*16 + lrow4 + r;
        size_t base = ((size_t)n*256 + orow)*L + l0 + wc*64 + lcol;
        #pragma unroll
        for (int nf = 0; nf < 4; ++nf) {
          size_t gi = base + (size_t)nf*16;
          outf[gi] = acc[mf][nf][r] + xres[gi];
        }
      }
  } else {
    ushort* outb = (ushort*)outp;
    #pragma unroll
    for (int mf = 0; mf < 4; ++mf)
      #pragma unroll
      for (int r = 0; r < 4; ++r) {
        int orow = o0 + wr*64 + mf*16 + lrow4 + r;
        size_t base = ((size_t)orow*ors + (size_t)n*ons)*L + l0 + wc*64 + lcol;
        #pragma unroll
        for (int nf = 0; nf < 4; ++nf)
          outb[base + (size_t)nf*16] = (ushort)f2bf(acc[mf][nf][r]);
      }
  }
}

// ---------------- context accumulation (no max subtraction needed) ---
__global__ __launch_bounds__(256) void k_ctx(float* __restrict__ ws)
{
  __shared__ float eb[32][257];
  __shared__ float vb[32][257];
  int t = threadIdx.x, bx = blockIdx.x;
  int nh = bx / 36, ch = bx % 36;
  int n = nh >> 3, h = nh & 7;
  int l0 = ch * 256;
  const ushort* keys = (const ushort*)((const char*)ws + B_KVPROJ);
  const ushort* vals = (const ushort*)((const char*)ws + B_QSM);
  for (int j = 0; j < 32; ++j){
    size_t gi = ((size_t)(h*32 + j)*8 + n)*L + l0 + t;
    eb[j][t] = __expf(__uint_as_float(((unsigned)keys[gi]) << 16));
    vb[j][t] = __uint_as_float(((unsigned)vals[gi]) << 16);
  }
  __syncthreads();
  int k = t >> 3, vg = t & 7;
  float d0=0.f, c0=0.f, c1=0.f, c2=0.f, c3=0.f;
  #pragma unroll 4
  for (int p = 0; p < 256; ++p){
    float e = eb[k][p];
    d0 += e;
    c0 = fmaf(e, vb[vg*4+0][p], c0);
    c1 = fmaf(e, vb[vg*4+1][p], c1);
    c2 = fmaf(e, vb[vg*4+2][p], c2);
    c3 = fmaf(e, vb[vg*4+3][p], c3);
  }
  float* ctx = ws + F_CTX + (size_t)nh*1024 + k*32 + vg*4;
  atomicAdd(ctx+0, c0); atomicAdd(ctx+1, c1);
  atomicAdd(ctx+2, c2); atomicAdd(ctx+3, c3);
  if (vg == 0) atomicAdd(ws + F_DENOM + nh*32 + k, d0);
}

// ---------------- M2 = Wp x ctx_norm^T per (n,h): [256 c][32 k] ------
__global__ __launch_bounds__(256) void k_m2(const float* __restrict__ Wp, float* __restrict__ ws)
{
  __shared__ float cn[32][32];
  int t = threadIdx.x, bx = blockIdx.x;
  int n = bx >> 3, h = bx & 7;
  int nh = bx;
  #pragma unroll
  for (int jj = 0; jj < 4; ++jj){
    int i = jj*256 + t;
    int k = i >> 5, v = i & 31;
    cn[k][v] = ws[F_CTX + (size_t)nh*1024 + i] / ws[F_DENOM + nh*32 + k];
  }
  __syncthreads();
  int c = t;
  const float* wrow = Wp + (size_t)c*256 + h*32;
  float w[32];
  #pragma unroll
  for (int v = 0; v < 32; ++v) w[v] = wrow[v];
  float* M2 = (float*)((char*)ws + B_M2) + ((size_t)n*256 + c)*256 + h*32;
  #pragma unroll 4
  for (int k = 0; k < 32; ++k){
    float s = 0.f;
    #pragma unroll
    for (int v = 0; v < 32; ++v) s = fmaf(w[v], cn[k][v], s);
    M2[k] = s;
  }
}

extern "C" void kernel_launch(void* const* d_in, const int* in_sizes, int n_in,
                              void* d_out, int out_size, void* d_ws, size_t ws_size,
                              hipStream_t stream)
{
  const float* q_in = (const float*)d_in[0];
  const float* kv   = (const float*)d_in[1];
  const float* Wq   = (const float*)d_in[2];
  const float* Wk   = (const float*)d_in[3];
  const float* Wv   = (const float*)d_in[4];
  const float* Wp   = (const float*)d_in[5];
  const float* qg   = (const float*)d_in[6];
  const float* qb   = (const float*)d_in[7];
  const float* kg   = (const float*)d_in[8];
  const float* kb   = (const float*)d_in[9];
  float* out = (float*)d_out;
  float* wsf = (float*)d_ws;
  ushort* kvproj = (ushort*)((char*)d_ws + B_KVPROJ);
  ushort* qsm    = (ushort*)((char*)d_ws + B_QSM);
  float*  M2f    = (float*)((char*)d_ws + B_M2);

  k_init<<<dim3(264), dim3(256), 0, stream>>>(wsf);
  k_stats<<<dim3(512), dim3(256), 0, stream>>>(q_in, kv, wsf);
  k_coef<<<dim3(2), dim3(256), 0, stream>>>(wsf, qg, qb, kg, kb);
  k_gemm<0><<<dim3(72,4,8), dim3(256), 0, stream>>>(Wk, Wv, 0, kv, wsf + F_COEF_KV, kvproj, nullptr, 8, 1);
  k_ctx<<<dim3(2304), dim3(256), 0, stream>>>(wsf);
  k_m2<<<dim3(64), dim3(256), 0, stream>>>(Wp, wsf);
  k_gemm<1><<<dim3(72,2,8), dim3(256), 0, stream>>>(Wq, Wq, 0, q_in, wsf + F_COEF_Q, qsm, nullptr, 1, 256);
  k_gemm<2><<<dim3(72,2,8), dim3(256), 0, stream>>>(M2f, M2f, 65536, qsm, nullptr, out, q_in, 1, 256);
}

// Round 3
// 333.698 us; speedup vs baseline: 19.3457x; 1.0970x over previous
//
#include <hip/hip_runtime.h>

#define L 9216
#define CNTF 73728.0f

// ws float-index offsets
#define F_COEF_Q 0
#define F_COEF_KV 512
#define F_DENOM 1024
#define F_CTX 3072
#define F_STATS 68608          // aliases keys block (dead before keys written)
// ws byte offsets
#define B_KVPROJ 274432u       // [512 o][8 n][9216 l] bf16 (keys 0-255, vals 256-511)
#define B_M2 278528u           // f32 [8 n][256 c][256 hk], aliases keys block (dead post k_ctx)
#define B_QSM 38023168u        // vals block; qsm [8 n][256 hk][9216 l] bf16 aliases post k_ctx

typedef float floatx4 __attribute__((ext_vector_type(4)));
typedef __bf16 bf16x8 __attribute__((ext_vector_type(8)));

__device__ __forceinline__ unsigned f2bf(float f){
  unsigned u = __float_as_uint(f);
  return (u + 0x7FFFu + ((u >> 16) & 1u)) >> 16;   // RNE bf16 (finite inputs)
}
__device__ __forceinline__ unsigned pack2(float lo, float hi){
  return f2bf(lo) | (f2bf(hi) << 16);
}
__device__ __forceinline__ int swz(int r){ return (r ^ (r >> 4)) & 7; }

// ---------------- init: zero denom + ctx + stats accumulators --------
__global__ __launch_bounds__(256) void k_init(float* __restrict__ ws){
  int i = blockIdx.x * 256 + threadIdx.x;
  if (i < 68608) ws[F_DENOM + i] = 0.0f;
}

// ---------------- BN stats: float4 + wave reduce + atomics -----------
__global__ __launch_bounds__(256) void k_stats(const float* __restrict__ q,
                                               const float* __restrict__ kv,
                                               float* __restrict__ ws){
  int b = blockIdx.x, t = threadIdx.x;     // 2048 blocks
  int ten = b >> 10;                       // 0: q, 1: kv
  int c = (b >> 2) & 255;
  int nc = b & 3;                          // n in {2nc, 2nc+1}
  const float* x = ten ? kv : q;
  const float4* p0 = (const float4*)(x + ((size_t)(2*nc)*256 + c)*L);
  const float4* p1 = (const float4*)(x + ((size_t)(2*nc+1)*256 + c)*L);
  float s = 0.f, ss = 0.f;
  for (int j = t; j < 2304; j += 256){
    float4 v = p0[j];
    s += v.x+v.y+v.z+v.w; ss += v.x*v.x+v.y*v.y+v.z*v.z+v.w*v.w;
  }
  for (int j = t; j < 2304; j += 256){
    float4 v = p1[j];
    s += v.x+v.y+v.z+v.w; ss += v.x*v.x+v.y*v.y+v.z*v.z+v.w*v.w;
  }
  #pragma unroll
  for (int off = 1; off < 64; off <<= 1){
    s += __shfl_xor(s, off); ss += __shfl_xor(ss, off);
  }
  __shared__ float r4[2][4];
  int w = t >> 6;
  if ((t & 63) == 0){ r4[0][w] = s; r4[1][w] = ss; }
  __syncthreads();
  if (t == 0){
    s  = r4[0][0]+r4[0][1]+r4[0][2]+r4[0][3];
    ss = r4[1][0]+r4[1][1]+r4[1][2]+r4[1][3];
    atomicAdd(&ws[F_STATS + ten*512 + c], s);
    atomicAdd(&ws[F_STATS + ten*512 + 256 + c], ss);
  }
}

// ---------------- BN coefficients: scale/shift per channel -----------
__global__ __launch_bounds__(256) void k_coef(float* __restrict__ ws,
    const float* __restrict__ qg, const float* __restrict__ qb,
    const float* __restrict__ kg, const float* __restrict__ kb){
  int t = blockIdx.x*256 + threadIdx.x;   // 0..511
  int ten = t >> 8, c = t & 255;
  float s  = ws[F_STATS + ten*512 + c];
  float ss = ws[F_STATS + ten*512 + 256 + c];
  float m = s * (1.0f/CNTF);
  float v = ss * (1.0f/CNTF) - m*m;
  float g  = ten ? kg[c] : qg[c];
  float be = ten ? kb[c] : qb[c];
  float sc = rsqrtf(v + 1e-3f) * g;
  ws[ten*512 + c] = sc;
  ws[ten*512 + 256 + c] = be - m*sc;
}

// ---------------- MFMA GEMM, B staged once at full K=256 -------------
// MODE 0: bf16 out (kvproj), OPS=4. MODE 1: softmax-over-32-rows epilogue,
// bf16 out (qsm), OPS=2. MODE 2: B is bf16 (qsm), f32 out + residual, OPS=2.
template<int MODE, int OPS>
__global__ __launch_bounds__(256) void k_gemm(
    const float* __restrict__ A0, const float* __restrict__ A1, size_t a_nstride,
    const void* __restrict__ Bsrc, const float* __restrict__ coef,
    void* __restrict__ outp, const float* __restrict__ xres,
    int ors, int ons)
{
  __shared__ __align__(16) ushort As[128*64];    // 16 KB: [o 128][k 64] swizzled
  __shared__ __align__(16) ushort Bs[128*256];   // 64 KB: [l 128][k 256] swizzled
  const int t = threadIdx.x;
  const int lane = t & 63, wid = t >> 6;
  const int wr = wid >> 1, wc = wid & 1;
  const int lp = blockIdx.x, n = blockIdx.z;
  const int l0 = lp * 128;

  const int arow = t >> 1, akh = t & 1;        // A stage: 2 threads/row
  const int cpair = t >> 3, lg = t & 7;        // B stage: k-pair, l-group

  // ---- stage B once (full K) ----
  #pragma unroll
  for (int kc = 0; kc < 4; ++kc){
    unsigned bu[16];
    int c = kc*64 + 2*cpair;
    if (MODE == 2) {
      const ushort* X = (const ushort*)Bsrc + ((size_t)n*256 + c)*L + l0 + lg*16;
      uint4 ra  = *(const uint4*)X;
      uint4 ra2 = *(const uint4*)(X + 8);
      uint4 rb  = *(const uint4*)(X + L);
      uint4 rb2 = *(const uint4*)(X + L + 8);
      bu[0] = (ra.x & 0xFFFFu) | (rb.x << 16);  bu[1] = (ra.x >> 16) | (rb.x & 0xFFFF0000u);
      bu[2] = (ra.y & 0xFFFFu) | (rb.y << 16);  bu[3] = (ra.y >> 16) | (rb.y & 0xFFFF0000u);
      bu[4] = (ra.z & 0xFFFFu) | (rb.z << 16);  bu[5] = (ra.z >> 16) | (rb.z & 0xFFFF0000u);
      bu[6] = (ra.w & 0xFFFFu) | (rb.w << 16);  bu[7] = (ra.w >> 16) | (rb.w & 0xFFFF0000u);
      bu[8]  = (ra2.x & 0xFFFFu) | (rb2.x << 16); bu[9]  = (ra2.x >> 16) | (rb2.x & 0xFFFF0000u);
      bu[10] = (ra2.y & 0xFFFFu) | (rb2.y << 16); bu[11] = (ra2.y >> 16) | (rb2.y & 0xFFFF0000u);
      bu[12] = (ra2.z & 0xFFFFu) | (rb2.z << 16); bu[13] = (ra2.z >> 16) | (rb2.z & 0xFFFF0000u);
      bu[14] = (ra2.w & 0xFFFFu) | (rb2.w << 16); bu[15] = (ra2.w >> 16) | (rb2.w & 0xFFFF0000u);
    } else {
      float s0 = coef[c],     h0 = coef[256 + c];
      float s1 = coef[c + 1], h1 = coef[256 + c + 1];
      const float* Xa = (const float*)Bsrc + ((size_t)n*256 + c)*L + l0 + lg*16;
      const float* Xb = Xa + L;
      #pragma unroll
      for (int q = 0; q < 4; ++q) {
        float4 a = ((const float4*)Xa)[q];
        float4 b = ((const float4*)Xb)[q];
        bu[4*q+0] = pack2(fmaf(a.x,s0,h0), fmaf(b.x,s1,h1));
        bu[4*q+1] = pack2(fmaf(a.y,s0,h0), fmaf(b.y,s1,h1));
        bu[4*q+2] = pack2(fmaf(a.z,s0,h0), fmaf(b.z,s1,h1));
        bu[4*q+3] = pack2(fmaf(a.w,s0,h0), fmaf(b.w,s1,h1));
      }
    }
    int chunk = kc*8 + (cpair >> 2);
    #pragma unroll
    for (int j = 0; j < 16; ++j){
      int ll = lg*16 + j;
      *(unsigned*)((char*)Bs + ll*512 + ((chunk ^ swz(ll))*16) + (cpair & 3)*4) = bu[j];
    }
  }

  const int lcol = lane & 15;
  const int lrow4 = (lane >> 4) * 4;

  for (int op = 0; op < OPS; ++op){
    const int o0 = op * 128;
    const float* Ablock;
    if (MODE == 0 && o0 >= 256) Ablock = A1 + (size_t)(o0 - 256) * 256;
    else                        Ablock = A0 + a_nstride * (size_t)n + (size_t)o0 * 256;

    floatx4 acc[4][4] = {};

    for (int kc = 0; kc < 4; ++kc) {
      // stage A chunk: W f32 -> bf16, swizzled b128 writes
      {
        const float4* asrc = (const float4*)(Ablock + (size_t)arow*256 + kc*64 + akh*32);
        unsigned au[16];
        #pragma unroll
        for (int q = 0; q < 8; ++q) {
          float4 v = asrc[q];
          au[2*q]   = pack2(v.x, v.y);
          au[2*q+1] = pack2(v.z, v.w);
        }
        #pragma unroll
        for (int q = 0; q < 4; ++q) {
          int gq = (akh*4 + q) ^ swz(arow);
          *(uint4*)((char*)As + arow*128 + gq*16) =
              make_uint4(au[4*q], au[4*q+1], au[4*q+2], au[4*q+3]);
        }
      }
      __syncthreads();
      #pragma unroll
      for (int ks = 0; ks < 2; ++ks) {
        bf16x8 af[4], bff[4];
        #pragma unroll
        for (int mf = 0; mf < 4; ++mf) {
          int row = wr*64 + mf*16 + lcol;
          int gq = (ks*4 + (lane >> 4)) ^ swz(row);
          af[mf] = *(const bf16x8*)((const char*)As + row*128 + gq*16);
        }
        #pragma unroll
        for (int nf = 0; nf < 4; ++nf) {
          int ll = wc*64 + nf*16 + lcol;
          int gq = (kc*8 + ks*4 + (lane >> 4)) ^ swz(ll);
          bff[nf] = *(const bf16x8*)((const char*)Bs + ll*512 + gq*16);
        }
        #pragma unroll
        for (int mf = 0; mf < 4; ++mf)
          #pragma unroll
          for (int nf = 0; nf < 4; ++nf)
            acc[mf][nf] = __builtin_amdgcn_mfma_f32_16x16x32_bf16(af[mf], bff[nf], acc[mf][nf], 0, 0, 0);
      }
      __syncthreads();
    }

    if (MODE == 1) {
      // softmax over the 32 rows of each head (wave tile = 64 rows = 2 heads)
      #pragma unroll
      for (int mf = 0; mf < 4; ++mf)
        #pragma unroll
        for (int nf = 0; nf < 4; ++nf)
          #pragma unroll
          for (int r = 0; r < 4; ++r)
            acc[mf][nf][r] = __expf(acc[mf][nf][r]);
      #pragma unroll
      for (int hg = 0; hg < 2; ++hg) {
        #pragma unroll
        for (int nf = 0; nf < 4; ++nf) {
          float s = 0.f;
          #pragma unroll
          for (int mh = 0; mh < 2; ++mh)
            #pragma unroll
            for (int r = 0; r < 4; ++r)
              s += acc[hg*2+mh][nf][r];
          s += __shfl_xor(s, 16);
          s += __shfl_xor(s, 32);
          float inv = 1.0f / s;
          #pragma unroll
          for (int mh = 0; mh < 2; ++mh)
            #pragma unroll
            for (int r = 0; r < 4; ++r)
              acc[hg*2+mh][nf][r] *= inv;
        }
      }
    }

    if (MODE == 2) {
      float* outf = (float*)outp;
      #pragma unroll
      for (int mf = 0; mf < 4; ++mf)
        #pragma unroll
        for (int r = 0; r < 4; ++r) {
          int orow = o0 + wr*64 + mf*16 + lrow4 + r;
          size_t base = ((size_t)n*256 + orow)*L + l0 + wc*64 + lcol;
          #pragma unroll
          for (int nf = 0; nf < 4; ++nf) {
            size_t gi = base + (size_t)nf*16;
            outf[gi] = acc[mf][nf][r] + xres[gi];
          }
        }
    } else {
      ushort* outb = (ushort*)outp;
      #pragma unroll
      for (int mf = 0; mf < 4; ++mf)
        #pragma unroll
        for (int r = 0; r < 4; ++r) {
          int orow = o0 + wr*64 + mf*16 + lrow4 + r;
          size_t base = ((size_t)orow*ors + (size_t)n*ons)*L + l0 + wc*64 + lcol;
          #pragma unroll
          for (int nf = 0; nf < 4; ++nf)
            outb[base + (size_t)nf*16] = (ushort)f2bf(acc[mf][nf][r]);
        }
    }
    if (op + 1 < OPS) __syncthreads();   // protect As before next op's stage
  }
}

// ---------------- context accumulation (uint-vectorized loads) -------
__global__ __launch_bounds__(256) void k_ctx(float* __restrict__ ws)
{
  __shared__ float eb[32][257];
  __shared__ float vb[32][257];
  int t = threadIdx.x, bx = blockIdx.x;
  int nh = bx / 36, ch = bx % 36;
  int n = nh >> 3, h = nh & 7;
  int l0 = ch * 256;
  const unsigned* keys = (const unsigned*)((const char*)ws + B_KVPROJ);
  const unsigned* vals = (const unsigned*)((const char*)ws + B_QSM);
  #pragma unroll
  for (int it = 0; it < 16; ++it){
    int i = it*256 + t;                 // 0..4095
    int row = i >> 7, c2 = i & 127;
    size_t gi = ((((size_t)(h*32 + row)*8 + n)*L + l0) >> 1) + c2;
    unsigned ku = keys[gi], vu = vals[gi];
    eb[row][2*c2]   = __expf(__uint_as_float(ku << 16));
    eb[row][2*c2+1] = __expf(__uint_as_float(ku & 0xFFFF0000u));
    vb[row][2*c2]   = __uint_as_float(vu << 16);
    vb[row][2*c2+1] = __uint_as_float(vu & 0xFFFF0000u);
  }
  __syncthreads();
  int k = t >> 3, vg = t & 7;
  float d0=0.f, c0=0.f, c1=0.f, c2=0.f, c3=0.f;
  #pragma unroll 4
  for (int p = 0; p < 256; ++p){
    float e = eb[k][p];
    d0 += e;
    c0 = fmaf(e, vb[vg*4+0][p], c0);
    c1 = fmaf(e, vb[vg*4+1][p], c1);
    c2 = fmaf(e, vb[vg*4+2][p], c2);
    c3 = fmaf(e, vb[vg*4+3][p], c3);
  }
  float* ctx = ws + F_CTX + (size_t)nh*1024 + k*32 + vg*4;
  atomicAdd(ctx+0, c0); atomicAdd(ctx+1, c1);
  atomicAdd(ctx+2, c2); atomicAdd(ctx+3, c3);
  if (vg == 0) atomicAdd(ws + F_DENOM + nh*32 + k, d0);
}

// ---------------- M2 = Wp x ctx_norm^T per (n,h): [256 c][32 k] ------
__global__ __launch_bounds__(256) void k_m2(const float* __restrict__ Wp, float* __restrict__ ws)
{
  __shared__ float cn[32][32];
  int t = threadIdx.x, bx = blockIdx.x;
  int n = bx >> 3, h = bx & 7;
  int nh = bx;
  #pragma unroll
  for (int jj = 0; jj < 4; ++jj){
    int i = jj*256 + t;
    int k = i >> 5, v = i & 31;
    cn[k][v] = ws[F_CTX + (size_t)nh*1024 + i] / ws[F_DENOM + nh*32 + k];
  }
  __syncthreads();
  int c = t;
  const float* wrow = Wp + (size_t)c*256 + h*32;
  float w[32];
  #pragma unroll
  for (int v = 0; v < 32; ++v) w[v] = wrow[v];
  float* M2 = (float*)((char*)ws + B_M2) + ((size_t)n*256 + c)*256 + h*32;
  #pragma unroll 4
  for (int k = 0; k < 32; ++k){
    float s = 0.f;
    #pragma unroll
    for (int v = 0; v < 32; ++v) s = fmaf(w[v], cn[k][v], s);
    M2[k] = s;
  }
}

extern "C" void kernel_launch(void* const* d_in, const int* in_sizes, int n_in,
                              void* d_out, int out_size, void* d_ws, size_t ws_size,
                              hipStream_t stream)
{
  const float* q_in = (const float*)d_in[0];
  const float* kv   = (const float*)d_in[1];
  const float* Wq   = (const float*)d_in[2];
  const float* Wk   = (const float*)d_in[3];
  const float* Wv   = (const float*)d_in[4];
  const float* Wp   = (const float*)d_in[5];
  const float* qg   = (const float*)d_in[6];
  const float* qb   = (const float*)d_in[7];
  const float* kg   = (const float*)d_in[8];
  const float* kb   = (const float*)d_in[9];
  float* out = (float*)d_out;
  float* wsf = (float*)d_ws;
  ushort* kvproj = (ushort*)((char*)d_ws + B_KVPROJ);
  ushort* qsm    = (ushort*)((char*)d_ws + B_QSM);
  float*  M2f    = (float*)((char*)d_ws + B_M2);

  k_init<<<dim3(268), dim3(256), 0, stream>>>(wsf);
  k_stats<<<dim3(2048), dim3(256), 0, stream>>>(q_in, kv, wsf);
  k_coef<<<dim3(2), dim3(256), 0, stream>>>(wsf, qg, qb, kg, kb);
  k_gemm<0,4><<<dim3(72,1,8), dim3(256), 0, stream>>>(Wk, Wv, 0, kv, wsf + F_COEF_KV, kvproj, nullptr, 8, 1);
  k_ctx<<<dim3(2304), dim3(256), 0, stream>>>(wsf);
  k_m2<<<dim3(64), dim3(256), 0, stream>>>(Wp, wsf);
  k_gemm<1,2><<<dim3(72,1,8), dim3(256), 0, stream>>>(Wq, Wq, 0, q_in, wsf + F_COEF_Q, qsm, nullptr, 1, 256);
  k_gemm<2,2><<<dim3(72,1,8), dim3(256), 0, stream>>>(M2f, M2f, 65536, qsm, nullptr, out, q_in, 1, 256);
}

// Round 4
// 222.999 us; speedup vs baseline: 28.9490x; 1.4964x over previous
//
#include <hip/hip_runtime.h>

#define L 9216
#define CNTF 73728.0f

// ws float-index offsets
#define F_DENOM 1024
#define F_CTX 3072
#define F_STATS 68608          // aliases keys block start (dead before kvproj writes)
// ws byte offsets
#define B_KVPROJ 274432u       // keys [256 o][8 n][9216 l] bf16, then vals (same size)
#define B_QSM 38023168u        // vals block; qsm [256 hk][8 n][9216 l] bf16 aliases post k_ctx
#define B_M2 274432u           // keys alias post-k_ctx: per-n 128KB pre-swizzled bf16 M2

// d_out byte aliases (dead until reproj finally overwrites everything)
#define O_WF 0u                // Wk'(128KB) Wv'(128KB) Wq'(128KB), pre-swizzled bf16
#define O_BIAS 393216u         // 768 f32: bk[256], bv[256], bq[256]

typedef float floatx4 __attribute__((ext_vector_type(4)));
typedef __bf16 bf16x8 __attribute__((ext_vector_type(8)));

__device__ __forceinline__ unsigned f2bf(float f){
  unsigned u = __float_as_uint(f);
  return (u + 0x7FFFu + ((u >> 16) & 1u)) >> 16;   // RNE bf16 (finite inputs)
}
__device__ __forceinline__ unsigned pack2(float lo, float hi){
  return f2bf(lo) | (f2bf(hi) << 16);
}
__device__ __forceinline__ int swz(int r){ return (r ^ (r >> 4)) & 7; }

__device__ __forceinline__ void gload16(const void* g, void* l){
  __builtin_amdgcn_global_load_lds(
      (const __attribute__((address_space(1))) unsigned*)g,
      (__attribute__((address_space(3))) unsigned*)l, 16, 0, 0);
}

// ---------------- init: zero denom + ctx + stats accumulators --------
__global__ __launch_bounds__(256) void k_init(float* __restrict__ ws){
  int i = blockIdx.x * 256 + threadIdx.x;
  if (i < 68608) ws[F_DENOM + i] = 0.0f;
}

// ---------------- BN stats: float4 + wave reduce + atomics -----------
__global__ __launch_bounds__(256) void k_stats(const float* __restrict__ q,
                                               const float* __restrict__ kv,
                                               float* __restrict__ ws){
  int b = blockIdx.x, t = threadIdx.x;     // 2048 blocks
  int ten = b >> 10;
  int c = (b >> 2) & 255;
  int nc = b & 3;
  const float* x = ten ? kv : q;
  const float4* p0 = (const float4*)(x + ((size_t)(2*nc)*256 + c)*L);
  const float4* p1 = (const float4*)(x + ((size_t)(2*nc+1)*256 + c)*L);
  float s = 0.f, ss = 0.f;
  for (int j = t; j < 2304; j += 256){
    float4 v = p0[j];
    s += v.x+v.y+v.z+v.w; ss += v.x*v.x+v.y*v.y+v.z*v.z+v.w*v.w;
  }
  for (int j = t; j < 2304; j += 256){
    float4 v = p1[j];
    s += v.x+v.y+v.z+v.w; ss += v.x*v.x+v.y*v.y+v.z*v.z+v.w*v.w;
  }
  #pragma unroll
  for (int off = 1; off < 64; off <<= 1){
    s += __shfl_xor(s, off); ss += __shfl_xor(ss, off);
  }
  __shared__ float r4[2][4];
  int w = t >> 6;
  if ((t & 63) == 0){ r4[0][w] = s; r4[1][w] = ss; }
  __syncthreads();
  if (t == 0){
    s  = r4[0][0]+r4[0][1]+r4[0][2]+r4[0][3];
    ss = r4[1][0]+r4[1][1]+r4[1][2]+r4[1][3];
    atomicAdd(&ws[F_STATS + ten*512 + c], s);
    atomicAdd(&ws[F_STATS + ten*512 + 256 + c], ss);
  }
}

// ---------------- BN coefficients: scale/shift per channel -----------
__global__ __launch_bounds__(256) void k_coef(float* __restrict__ ws,
    const float* __restrict__ qg, const float* __restrict__ qb,
    const float* __restrict__ kg, const float* __restrict__ kb){
  int t = blockIdx.x*256 + threadIdx.x;   // 0..511
  int ten = t >> 8, c = t & 255;
  float s  = ws[F_STATS + ten*512 + c];
  float ss = ws[F_STATS + ten*512 + 256 + c];
  float m = s * (1.0f/CNTF);
  float v = ss * (1.0f/CNTF) - m*m;
  float g  = ten ? kg[c] : qg[c];
  float be = ten ? kb[c] : qb[c];
  float sc = rsqrtf(v + 1e-3f) * g;
  ws[ten*512 + c] = sc;            // q: [0..255]=sc [256..511]=sh ; kv at +512
  ws[ten*512 + 256 + c] = be - m*sc;
}

// ---------------- fold BN into weights: W' bf16 pre-swizzled + bias --
__global__ __launch_bounds__(256) void k_wfold(const float* __restrict__ W0,
    const float* __restrict__ W1, const float* __restrict__ W2,
    const float* __restrict__ ws, char* __restrict__ outa){
  int b = blockIdx.x, r = threadIdx.x;
  const float* W = (b == 0) ? W0 : ((b == 1) ? W1 : W2);
  const float* coef = (b < 2) ? ws + 512 : ws;
  const float* wrow = W + (size_t)r * 256;
  char* chunk = outa + O_WF + (size_t)b * 131072;
  int opl = r >> 7, rl = r & 127;
  float bias = 0.f;
  for (int kc = 0; kc < 4; ++kc){
    unsigned pk[8][4];
    #pragma unroll
    for (int g = 0; g < 8; ++g){
      float v[8];
      #pragma unroll
      for (int m = 0; m < 8; ++m){
        int k = kc*64 + g*8 + m;
        float w = wrow[k];
        v[m] = w * coef[k];
        bias = fmaf(w, coef[256 + k], bias);
      }
      pk[g][0] = pack2(v[0], v[1]); pk[g][1] = pack2(v[2], v[3]);
      pk[g][2] = pack2(v[4], v[5]); pk[g][3] = pack2(v[6], v[7]);
    }
    #pragma unroll
    for (int g = 0; g < 8; ++g){
      int idx = (opl*4 + kc)*1024 + rl*8 + (g ^ swz(rl));
      *(uint4*)(chunk + (size_t)idx*16) =
          make_uint4(pk[g][0], pk[g][1], pk[g][2], pk[g][3]);
    }
  }
  ((float*)(outa + O_BIAS))[b*256 + r] = bias;
}

// ---------------- MFMA GEMM: 128x128 tile, A via global_load_lds -----
// MODE 0: bf16 out + bias (kvproj). MODE 1: bias + softmax-over-32-rows,
// bf16 out (qsm). MODE 2: B bf16 (qsm), f32 out + residual.
template<int MODE>
__global__ __launch_bounds__(256, 3) void k_gemm(
    const char* __restrict__ Af, size_t a_nstride,
    const void* __restrict__ Bsrc,
    const float* __restrict__ bias,
    void* __restrict__ outp, const float* __restrict__ xres,
    int ors, int ons)
{
  __shared__ __align__(16) ushort As[128*64];    // 16 KB [r][g'] swizzled
  __shared__ __align__(16) ushort Bs[128*64];    // 16 KB [l][g'] swizzled
  const int t = threadIdx.x;
  const int lane = t & 63, wid = t >> 6;
  const int wr = wid >> 1, wc = wid & 1;
  const int lp = blockIdx.x, op = blockIdx.y, n = blockIdx.z;
  const int l0 = lp * 128, o0 = op * 128;
  const char* Achunk = Af + (size_t)n * a_nstride + (size_t)op * 65536;

  const int cpair = t >> 3, lg = t & 7;
  const int lcol = lane & 15, lhi = lane >> 4;

  floatx4 acc[4][4] = {};

  for (int kc = 0; kc < 4; ++kc) {
    // ---- A: async global->LDS, pre-swizzled image, zero VALU
    {
      const char* src = Achunk + kc*16384 + ((size_t)(wid*4*64 + lane))*16;
      ushort* dst = As + wid*4*512;              // wave-uniform base
      gload16(src,        dst);
      gload16(src + 1024, dst + 512);
      gload16(src + 2048, dst + 1024);
      gload16(src + 3072, dst + 1536);
    }
    // ---- B: reg-stage (convert/transpose) -> swizzled ds_write
    unsigned bu[16];
    if (MODE == 2) {
      const ushort* X = (const ushort*)Bsrc + ((size_t)(n*256 + kc*64 + 2*cpair))*L + l0 + lg*16;
      uint4 ra  = *(const uint4*)X;
      uint4 ra2 = *(const uint4*)(X + 8);
      uint4 rb  = *(const uint4*)(X + L);
      uint4 rb2 = *(const uint4*)(X + L + 8);
      bu[0] = (ra.x & 0xFFFFu) | (rb.x << 16);  bu[1] = (ra.x >> 16) | (rb.x & 0xFFFF0000u);
      bu[2] = (ra.y & 0xFFFFu) | (rb.y << 16);  bu[3] = (ra.y >> 16) | (rb.y & 0xFFFF0000u);
      bu[4] = (ra.z & 0xFFFFu) | (rb.z << 16);  bu[5] = (ra.z >> 16) | (rb.z & 0xFFFF0000u);
      bu[6] = (ra.w & 0xFFFFu) | (rb.w << 16);  bu[7] = (ra.w >> 16) | (rb.w & 0xFFFF0000u);
      bu[8]  = (ra2.x & 0xFFFFu) | (rb2.x << 16); bu[9]  = (ra2.x >> 16) | (rb2.x & 0xFFFF0000u);
      bu[10] = (ra2.y & 0xFFFFu) | (rb2.y << 16); bu[11] = (ra2.y >> 16) | (rb2.y & 0xFFFF0000u);
      bu[12] = (ra2.z & 0xFFFFu) | (rb2.z << 16); bu[13] = (ra2.z >> 16) | (rb2.z & 0xFFFF0000u);
      bu[14] = (ra2.w & 0xFFFFu) | (rb2.w << 16); bu[15] = (ra2.w >> 16) | (rb2.w & 0xFFFF0000u);
    } else {
      const float* Xa = (const float*)Bsrc + ((size_t)(n*256 + kc*64 + 2*cpair))*L + l0 + lg*16;
      const float* Xb = Xa + L;
      #pragma unroll
      for (int q = 0; q < 4; ++q) {
        float4 a = ((const float4*)Xa)[q];
        float4 b = ((const float4*)Xb)[q];
        bu[4*q+0] = pack2(a.x, b.x);
        bu[4*q+1] = pack2(a.y, b.y);
        bu[4*q+2] = pack2(a.z, b.z);
        bu[4*q+3] = pack2(a.w, b.w);
      }
    }
    {
      int g = cpair >> 2, d = cpair & 3;
      #pragma unroll
      for (int j = 0; j < 16; ++j){
        int ll = lg*16 + j;
        *(unsigned*)((char*)Bs + ll*128 + ((g ^ swz(ll))*16) + d*4) = bu[j];
      }
    }
    __syncthreads();   // drains vmcnt (A in LDS) + lgkm (B writes)
    // ---- compute
    #pragma unroll
    for (int ks = 0; ks < 2; ++ks) {
      bf16x8 af[4], bfr[4];
      #pragma unroll
      for (int mf = 0; mf < 4; ++mf) {
        int row = wr*64 + mf*16 + lcol;
        int gq = (ks*4 + lhi) ^ swz(row);
        af[mf] = *(const bf16x8*)(As + row*64 + gq*8);
      }
      #pragma unroll
      for (int nf = 0; nf < 4; ++nf) {
        int ll = wc*64 + nf*16 + lcol;
        int gq = (ks*4 + lhi) ^ swz(ll);
        bfr[nf] = *(const bf16x8*)(Bs + ll*64 + gq*8);
      }
      #pragma unroll
      for (int mf = 0; mf < 4; ++mf)
        #pragma unroll
        for (int nf = 0; nf < 4; ++nf)
          acc[mf][nf] = __builtin_amdgcn_mfma_f32_16x16x32_bf16(af[mf], bfr[nf], acc[mf][nf], 0, 0, 0);
    }
    __syncthreads();
  }

  const int lrow4 = lhi * 4;

  if (MODE == 1) {
    // bias + exp, then softmax over the 32 rows of each head
    #pragma unroll
    for (int mf = 0; mf < 4; ++mf)
      #pragma unroll
      for (int r = 0; r < 4; ++r) {
        float bv = bias[o0 + wr*64 + mf*16 + lrow4 + r];
        #pragma unroll
        for (int nf = 0; nf < 4; ++nf)
          acc[mf][nf][r] = __expf(acc[mf][nf][r] + bv);
      }
    #pragma unroll
    for (int hg = 0; hg < 2; ++hg) {
      #pragma unroll
      for (int nf = 0; nf < 4; ++nf) {
        float s = 0.f;
        #pragma unroll
        for (int mh = 0; mh < 2; ++mh)
          #pragma unroll
          for (int r = 0; r < 4; ++r)
            s += acc[hg*2+mh][nf][r];
        s += __shfl_xor(s, 16);
        s += __shfl_xor(s, 32);
        float inv = 1.0f / s;
        #pragma unroll
        for (int mh = 0; mh < 2; ++mh)
          #pragma unroll
          for (int r = 0; r < 4; ++r)
            acc[hg*2+mh][nf][r] *= inv;
      }
    }
  }

  if (MODE == 2) {
    float* outf = (float*)outp;
    #pragma unroll
    for (int mf = 0; mf < 4; ++mf)
      #pragma unroll
      for (int r = 0; r < 4; ++r) {
        int orow = o0 + wr*64 + mf*16 + lrow4 + r;
        size_t base = ((size_t)n*256 + orow)*L + l0 + wc*64 + lcol;
        #pragma unroll
        for (int nf = 0; nf < 4; ++nf) {
          size_t gi = base + (size_t)nf*16;
          outf[gi] = acc[mf][nf][r] + xres[gi];
        }
      }
  } else {
    ushort* outb = (ushort*)outp;
    #pragma unroll
    for (int mf = 0; mf < 4; ++mf)
      #pragma unroll
      for (int r = 0; r < 4; ++r) {
        int orow = o0 + wr*64 + mf*16 + lrow4 + r;
        float bv = (MODE == 0) ? bias[orow] : 0.f;
        size_t base = ((size_t)orow*ors + (size_t)n*ons)*L + l0 + wc*64 + lcol;
        #pragma unroll
        for (int nf = 0; nf < 4; ++nf)
          outb[base + (size_t)nf*16] = (ushort)f2bf(acc[mf][nf][r] + bv);
      }
  }
}

// ---------------- context accumulation (float4 LDS reads) ------------
__global__ __launch_bounds__(256) void k_ctx(float* __restrict__ ws)
{
  __shared__ float eb[32][260];
  __shared__ float vb[32][260];
  int t = threadIdx.x, bx = blockIdx.x;
  int nh = bx / 36, ch = bx % 36;
  int n = nh >> 3, h = nh & 7;
  int l0 = ch * 256;
  const unsigned* keys = (const unsigned*)((const char*)ws + B_KVPROJ);
  const unsigned* vals = (const unsigned*)((const char*)ws + B_QSM);
  #pragma unroll
  for (int it = 0; it < 16; ++it){
    int i = it*256 + t;
    int row = i >> 7, c2 = i & 127;
    size_t gi = ((((size_t)(h*32 + row)*8 + n)*L + l0) >> 1) + c2;
    unsigned ku = keys[gi], vu = vals[gi];
    eb[row][2*c2]   = __expf(__uint_as_float(ku << 16));
    eb[row][2*c2+1] = __expf(__uint_as_float(ku & 0xFFFF0000u));
    vb[row][2*c2]   = __uint_as_float(vu << 16);
    vb[row][2*c2+1] = __uint_as_float(vu & 0xFFFF0000u);
  }
  __syncthreads();
  int k = t >> 3, vg = t & 7;       // thread: (k, v in {vg, vg+8, vg+16, vg+24})
  float d0=0.f, c0=0.f, c1=0.f, c2a=0.f, c3=0.f;
  for (int p = 0; p < 256; p += 4){
    float4 e  = *(const float4*)&eb[k][p];
    float4 v0 = *(const float4*)&vb[vg     ][p];
    float4 v1 = *(const float4*)&vb[vg + 8 ][p];
    float4 v2 = *(const float4*)&vb[vg + 16][p];
    float4 v3 = *(const float4*)&vb[vg + 24][p];
    d0 += e.x + e.y + e.z + e.w;
    c0 = fmaf(e.x,v0.x,fmaf(e.y,v0.y,fmaf(e.z,v0.z,fmaf(e.w,v0.w,c0))));
    c1 = fmaf(e.x,v1.x,fmaf(e.y,v1.y,fmaf(e.z,v1.z,fmaf(e.w,v1.w,c1))));
    c2a= fmaf(e.x,v2.x,fmaf(e.y,v2.y,fmaf(e.z,v2.z,fmaf(e.w,v2.w,c2a))));
    c3 = fmaf(e.x,v3.x,fmaf(e.y,v3.y,fmaf(e.z,v3.z,fmaf(e.w,v3.w,c3))));
  }
  float* ctx = ws + F_CTX + (size_t)nh*1024 + k*32;
  atomicAdd(ctx + vg,      c0);
  atomicAdd(ctx + vg + 8,  c1);
  atomicAdd(ctx + vg + 16, c2a);
  atomicAdd(ctx + vg + 24, c3);
  if (vg == 0) atomicAdd(ws + F_DENOM + nh*32 + k, d0);
}

// ---------------- M2 = Wp x ctx_norm^T, bf16 pre-swizzled per n ------
__global__ __launch_bounds__(256) void k_m2(const float* __restrict__ Wp,
                                            float* __restrict__ ws)
{
  __shared__ float cn[32][33];
  int t = threadIdx.x, bx = blockIdx.x;
  int n = bx >> 3, h = bx & 7;
  int nh = bx;
  #pragma unroll
  for (int jj = 0; jj < 4; ++jj){
    int i = jj*256 + t;
    int k = i >> 5, v = i & 31;
    cn[k][v] = ws[F_CTX + (size_t)nh*1024 + i] / ws[F_DENOM + nh*32 + k];
  }
  __syncthreads();
  int c = t;
  const float* wrow = Wp + (size_t)c*256 + h*32;
  float w[32];
  #pragma unroll
  for (int v = 0; v < 32; ++v) w[v] = wrow[v];
  float s[32];
  #pragma unroll
  for (int k = 0; k < 32; ++k){
    float a = 0.f;
    #pragma unroll
    for (int v = 0; v < 32; ++v) a = fmaf(w[v], cn[k][v], a);
    s[k] = a;
  }
  char* base = (char*)ws + B_M2 + (size_t)n*131072;
  int opl = c >> 7, rl = c & 127, kc = h >> 1;
  #pragma unroll
  for (int gg = 0; gg < 4; ++gg){
    int g = (h & 1)*4 + gg;
    uint4 u = make_uint4(pack2(s[gg*8+0], s[gg*8+1]), pack2(s[gg*8+2], s[gg*8+3]),
                         pack2(s[gg*8+4], s[gg*8+5]), pack2(s[gg*8+6], s[gg*8+7]));
    *(uint4*)(base + (size_t)((opl*4 + kc)*1024 + rl*8 + (g ^ swz(rl)))*16) = u;
  }
}

extern "C" void kernel_launch(void* const* d_in, const int* in_sizes, int n_in,
                              void* d_out, int out_size, void* d_ws, size_t ws_size,
                              hipStream_t stream)
{
  const float* q_in = (const float*)d_in[0];
  const float* kv   = (const float*)d_in[1];
  const float* Wq   = (const float*)d_in[2];
  const float* Wk   = (const float*)d_in[3];
  const float* Wv   = (const float*)d_in[4];
  const float* Wp   = (const float*)d_in[5];
  const float* qg   = (const float*)d_in[6];
  const float* qb   = (const float*)d_in[7];
  const float* kg   = (const float*)d_in[8];
  const float* kb   = (const float*)d_in[9];
  float* out = (float*)d_out;
  float* wsf = (float*)d_ws;
  char*  outa = (char*)d_out;
  ushort* kvproj = (ushort*)((char*)d_ws + B_KVPROJ);
  ushort* qsm    = (ushort*)((char*)d_ws + B_QSM);
  const float* biasf = (const float*)(outa + O_BIAS);

  k_init <<<dim3(268),  dim3(256), 0, stream>>>(wsf);
  k_stats<<<dim3(2048), dim3(256), 0, stream>>>(q_in, kv, wsf);
  k_coef <<<dim3(2),    dim3(256), 0, stream>>>(wsf, qg, qb, kg, kb);
  k_wfold<<<dim3(3),    dim3(256), 0, stream>>>(Wk, Wv, Wq, wsf, outa);
  k_gemm<0><<<dim3(72,4,8), dim3(256), 0, stream>>>(outa + O_WF, 0, kv,
      biasf, kvproj, nullptr, 8, 1);
  k_ctx  <<<dim3(2304), dim3(256), 0, stream>>>(wsf);
  k_m2   <<<dim3(64),   dim3(256), 0, stream>>>(Wp, wsf);
  k_gemm<1><<<dim3(72,2,8), dim3(256), 0, stream>>>(outa + O_WF + 262144, 0, q_in,
      biasf + 512, qsm, nullptr, 1, 256);
  k_gemm<2><<<dim3(72,2,8), dim3(256), 0, stream>>>((char*)d_ws + B_M2, 131072, qsm,
      nullptr, out, q_in, 1, 256);
}

// Round 5
// 215.722 us; speedup vs baseline: 29.9255x; 1.0337x over previous
//
#include <hip/hip_runtime.h>

#define L 9216
#define CNTF 73728.0f

// ws float-index offsets
#define F_DENOM 1024
#define F_CTX 3072
#define F_STATS 68608          // aliases keys block start (dead before kvproj writes)
// ws byte offsets
#define B_KVPROJ 274432u       // keys [256 o][8 n][9216 l] bf16, then vals (same size)
#define B_QSM 38023168u        // vals block; qsm [256 hk][8 n][9216 l] bf16 aliases post k_ctx
#define B_M2 274432u           // keys alias post-k_ctx: per-n 128KB pre-swizzled bf16 M2

// d_out byte aliases (dead until reproj finally overwrites everything)
#define O_WF 0u                // Wk'(128KB) Wv'(128KB) Wq'(128KB), pre-swizzled bf16
#define O_BIAS 393216u         // 768 f32: bk[256], bv[256], bq[256]

typedef float floatx4 __attribute__((ext_vector_type(4)));
typedef __bf16 bf16x8 __attribute__((ext_vector_type(8)));

__device__ __forceinline__ unsigned short f2bf(float f){
  return __builtin_bit_cast(unsigned short, (__bf16)f);   // RNE, compiler cvt
}
__device__ __forceinline__ unsigned pack2(float lo, float hi){
  return (unsigned)f2bf(lo) | ((unsigned)f2bf(hi) << 16); // -> v_cvt_pk_bf16_f32
}
__device__ __forceinline__ int swz(int r){ return (r ^ (r >> 4)) & 7; }

__device__ __forceinline__ void gload16(const void* g, void* l){
  __builtin_amdgcn_global_load_lds(
      (const __attribute__((address_space(1))) unsigned*)g,
      (__attribute__((address_space(3))) unsigned*)l, 16, 0, 0);
}

// ---------------- init: zero denom + ctx + stats accumulators --------
__global__ __launch_bounds__(256) void k_init(float* __restrict__ ws){
  int i = blockIdx.x * 256 + threadIdx.x;
  if (i < 68608) ws[F_DENOM + i] = 0.0f;
}

// ---------------- BN stats: deep-batched float4 + wave reduce --------
__global__ __launch_bounds__(256) void k_stats(const float* __restrict__ q,
                                               const float* __restrict__ kv,
                                               float* __restrict__ ws){
  int b = blockIdx.x, t = threadIdx.x;     // 2048 blocks
  int ten = b >> 10;
  int c = (b >> 2) & 255;
  int nc = b & 3;
  const float* x = ten ? kv : q;
  const float4* p0 = (const float4*)(x + ((size_t)(2*nc)*256 + c)*L);
  const float4* p1 = (const float4*)(x + ((size_t)(2*nc+1)*256 + c)*L);
  float4 v[18];
  #pragma unroll
  for (int j = 0; j < 9; ++j) v[j] = p0[t + 256*j];
  #pragma unroll
  for (int j = 0; j < 9; ++j) v[9+j] = p1[t + 256*j];
  float s = 0.f, ss = 0.f;
  #pragma unroll
  for (int j = 0; j < 18; ++j){
    s  += v[j].x + v[j].y + v[j].z + v[j].w;
    ss += v[j].x*v[j].x + v[j].y*v[j].y + v[j].z*v[j].z + v[j].w*v[j].w;
  }
  #pragma unroll
  for (int off = 1; off < 64; off <<= 1){
    s += __shfl_xor(s, off); ss += __shfl_xor(ss, off);
  }
  __shared__ float r4[2][4];
  int w = t >> 6;
  if ((t & 63) == 0){ r4[0][w] = s; r4[1][w] = ss; }
  __syncthreads();
  if (t == 0){
    s  = r4[0][0]+r4[0][1]+r4[0][2]+r4[0][3];
    ss = r4[1][0]+r4[1][1]+r4[1][2]+r4[1][3];
    atomicAdd(&ws[F_STATS + ten*512 + c], s);
    atomicAdd(&ws[F_STATS + ten*512 + 256 + c], ss);
  }
}

// -------- fold BN into weights (coef computed in-block): W' + bias ---
__global__ __launch_bounds__(256) void k_wfold(const float* __restrict__ W0,
    const float* __restrict__ W1, const float* __restrict__ W2,
    const float* __restrict__ ws,
    const float* __restrict__ qg, const float* __restrict__ qb,
    const float* __restrict__ kg, const float* __restrict__ kb,
    char* __restrict__ outa){
  __shared__ float sc[256], sh[256];
  int b = blockIdx.x, r = threadIdx.x;
  int tsel = (b < 2) ? 1 : 0;                 // Wk,Wv use kv stats; Wq uses q
  {
    float s  = ws[F_STATS + tsel*512 + r];
    float ssum = ws[F_STATS + tsel*512 + 256 + r];
    float m = s * (1.0f/CNTF);
    float vv = ssum * (1.0f/CNTF) - m*m;
    float g  = tsel ? kg[r] : qg[r];
    float be = tsel ? kb[r] : qb[r];
    float scv = rsqrtf(vv + 1e-3f) * g;
    sc[r] = scv; sh[r] = be - m*scv;
  }
  __syncthreads();
  const float* W = (b == 0) ? W0 : ((b == 1) ? W1 : W2);
  const float* wrow = W + (size_t)r * 256;
  char* chunk = outa + O_WF + (size_t)b * 131072;
  int opl = r >> 7, rl = r & 127;
  float bias = 0.f;
  for (int kc = 0; kc < 4; ++kc){
    unsigned pk[8][4];
    #pragma unroll
    for (int g = 0; g < 8; ++g){
      float v[8];
      #pragma unroll
      for (int m = 0; m < 8; ++m){
        int k = kc*64 + g*8 + m;
        float w = wrow[k];
        v[m] = w * sc[k];
        bias = fmaf(w, sh[k], bias);
      }
      pk[g][0] = pack2(v[0], v[1]); pk[g][1] = pack2(v[2], v[3]);
      pk[g][2] = pack2(v[4], v[5]); pk[g][3] = pack2(v[6], v[7]);
    }
    #pragma unroll
    for (int g = 0; g < 8; ++g){
      int idx = (opl*4 + kc)*1024 + rl*8 + (g ^ swz(rl));
      *(uint4*)(chunk + (size_t)idx*16) =
          make_uint4(pk[g][0], pk[g][1], pk[g][2], pk[g][3]);
    }
  }
  ((float*)(outa + O_BIAS))[b*256 + r] = bias;
}

// ---------------- MFMA GEMM: 128x128 tile, A via global_load_lds -----
// MODE 0: bf16 out + bias (kvproj). MODE 1: bias + softmax-over-32-rows,
// bf16 out (qsm). MODE 2: B bf16 (qsm), f32 out + residual.
template<int MODE>
__global__ __launch_bounds__(256, 3) void k_gemm(
    const char* __restrict__ Af, size_t a_nstride,
    const void* __restrict__ Bsrc,
    const float* __restrict__ bias,
    void* __restrict__ outp, const float* __restrict__ xres,
    int ors, int ons)
{
  __shared__ __align__(16) ushort As[128*64];    // 16 KB [r][g'] swizzled
  __shared__ __align__(16) ushort Bs[128*64];    // 16 KB [l][g'] swizzled
  const int t = threadIdx.x;
  const int lane = t & 63, wid = t >> 6;
  const int wr = wid >> 1, wc = wid & 1;
  const int lp = blockIdx.x, op = blockIdx.y, n = blockIdx.z;
  const int l0 = lp * 128, o0 = op * 128;
  const char* Achunk = Af + (size_t)n * a_nstride + (size_t)op * 65536;

  const int cpair = t >> 3, lg = t & 7;
  const int lcol = lane & 15, lhi = lane >> 4;

  floatx4 acc[4][4] = {};

  for (int kc = 0; kc < 4; ++kc) {
    // ---- A: async global->LDS, pre-swizzled image, zero VALU
    {
      const char* src = Achunk + kc*16384 + ((size_t)(wid*4*64 + lane))*16;
      ushort* dst = As + wid*4*512;              // wave-uniform base
      gload16(src,        dst);
      gload16(src + 1024, dst + 512);
      gload16(src + 2048, dst + 1024);
      gload16(src + 3072, dst + 1536);
    }
    // ---- B: reg-stage (convert/transpose) -> swizzled ds_write
    unsigned bu[16];
    if (MODE == 2) {
      const ushort* X = (const ushort*)Bsrc + ((size_t)(n*256 + kc*64 + 2*cpair))*L + l0 + lg*16;
      uint4 ra  = *(const uint4*)X;
      uint4 ra2 = *(const uint4*)(X + 8);
      uint4 rb  = *(const uint4*)(X + L);
      uint4 rb2 = *(const uint4*)(X + L + 8);
      bu[0] = (ra.x & 0xFFFFu) | (rb.x << 16);  bu[1] = (ra.x >> 16) | (rb.x & 0xFFFF0000u);
      bu[2] = (ra.y & 0xFFFFu) | (rb.y << 16);  bu[3] = (ra.y >> 16) | (rb.y & 0xFFFF0000u);
      bu[4] = (ra.z & 0xFFFFu) | (rb.z << 16);  bu[5] = (ra.z >> 16) | (rb.z & 0xFFFF0000u);
      bu[6] = (ra.w & 0xFFFFu) | (rb.w << 16);  bu[7] = (ra.w >> 16) | (rb.w & 0xFFFF0000u);
      bu[8]  = (ra2.x & 0xFFFFu) | (rb2.x << 16); bu[9]  = (ra2.x >> 16) | (rb2.x & 0xFFFF0000u);
      bu[10] = (ra2.y & 0xFFFFu) | (rb2.y << 16); bu[11] = (ra2.y >> 16) | (rb2.y & 0xFFFF0000u);
      bu[12] = (ra2.z & 0xFFFFu) | (rb2.z << 16); bu[13] = (ra2.z >> 16) | (rb2.z & 0xFFFF0000u);
      bu[14] = (ra2.w & 0xFFFFu) | (rb2.w << 16); bu[15] = (ra2.w >> 16) | (rb2.w & 0xFFFF0000u);
    } else {
      const float* Xa = (const float*)Bsrc + ((size_t)(n*256 + kc*64 + 2*cpair))*L + l0 + lg*16;
      const float* Xb = Xa + L;
      #pragma unroll
      for (int q = 0; q < 4; ++q) {
        float4 a = ((const float4*)Xa)[q];
        float4 b = ((const float4*)Xb)[q];
        bu[4*q+0] = pack2(a.x, b.x);
        bu[4*q+1] = pack2(a.y, b.y);
        bu[4*q+2] = pack2(a.z, b.z);
        bu[4*q+3] = pack2(a.w, b.w);
      }
    }
    {
      int g = cpair >> 2, d = cpair & 3;
      #pragma unroll
      for (int j = 0; j < 16; ++j){
        int ll = lg*16 + j;
        *(unsigned*)((char*)Bs + ll*128 + ((g ^ swz(ll))*16) + d*4) = bu[j];
      }
    }
    __syncthreads();   // drains vmcnt (A in LDS) + lgkm (B writes)
    // ---- compute
    #pragma unroll
    for (int ks = 0; ks < 2; ++ks) {
      bf16x8 af[4], bfr[4];
      #pragma unroll
      for (int mf = 0; mf < 4; ++mf) {
        int row = wr*64 + mf*16 + lcol;
        int gq = (ks*4 + lhi) ^ swz(row);
        af[mf] = *(const bf16x8*)(As + row*64 + gq*8);
      }
      #pragma unroll
      for (int nf = 0; nf < 4; ++nf) {
        int ll = wc*64 + nf*16 + lcol;
        int gq = (ks*4 + lhi) ^ swz(ll);
        bfr[nf] = *(const bf16x8*)(Bs + ll*64 + gq*8);
      }
      #pragma unroll
      for (int mf = 0; mf < 4; ++mf)
        #pragma unroll
        for (int nf = 0; nf < 4; ++nf)
          acc[mf][nf] = __builtin_amdgcn_mfma_f32_16x16x32_bf16(af[mf], bfr[nf], acc[mf][nf], 0, 0, 0);
    }
    __syncthreads();
  }

  const int lrow4 = lhi * 4;

  if (MODE == 1) {
    // bias + exp, then softmax over the 32 rows of each head
    #pragma unroll
    for (int mf = 0; mf < 4; ++mf)
      #pragma unroll
      for (int r = 0; r < 4; ++r) {
        float bv = bias[o0 + wr*64 + mf*16 + lrow4 + r];
        #pragma unroll
        for (int nf = 0; nf < 4; ++nf)
          acc[mf][nf][r] = __expf(acc[mf][nf][r] + bv);
      }
    #pragma unroll
    for (int hg = 0; hg < 2; ++hg) {
      #pragma unroll
      for (int nf = 0; nf < 4; ++nf) {
        float s = 0.f;
        #pragma unroll
        for (int mh = 0; mh < 2; ++mh)
          #pragma unroll
          for (int r = 0; r < 4; ++r)
            s += acc[hg*2+mh][nf][r];
        s += __shfl_xor(s, 16);
        s += __shfl_xor(s, 32);
        float inv = 1.0f / s;
        #pragma unroll
        for (int mh = 0; mh < 2; ++mh)
          #pragma unroll
          for (int r = 0; r < 4; ++r)
            acc[hg*2+mh][nf][r] *= inv;
      }
    }
  }

  if (MODE == 2) {
    float* outf = (float*)outp;
    #pragma unroll
    for (int mf = 0; mf < 4; ++mf)
      #pragma unroll
      for (int r = 0; r < 4; ++r) {
        int orow = o0 + wr*64 + mf*16 + lrow4 + r;
        size_t base = ((size_t)n*256 + orow)*L + l0 + wc*64 + lcol;
        #pragma unroll
        for (int nf = 0; nf < 4; ++nf) {
          size_t gi = base + (size_t)nf*16;
          outf[gi] = acc[mf][nf][r] + xres[gi];
        }
      }
  } else {
    ushort* outb = (ushort*)outp;
    #pragma unroll
    for (int mf = 0; mf < 4; ++mf)
      #pragma unroll
      for (int r = 0; r < 4; ++r) {
        int orow = o0 + wr*64 + mf*16 + lrow4 + r;
        float bv = (MODE == 0) ? bias[orow] : 0.f;
        size_t base = ((size_t)orow*ors + (size_t)n*ons)*L + l0 + wc*64 + lcol;
        #pragma unroll
        for (int nf = 0; nf < 4; ++nf)
          outb[base + (size_t)nf*16] = f2bf(acc[mf][nf][r] + bv);
      }
  }
}

// ---------------- context accumulation (uint4 global loads) ----------
__global__ __launch_bounds__(256) void k_ctx(float* __restrict__ ws)
{
  __shared__ float eb[32][260];
  __shared__ float vb[32][260];
  int t = threadIdx.x, bx = blockIdx.x;
  int nh = bx / 36, ch = bx % 36;
  int n = nh >> 3, h = nh & 7;
  int l0 = ch * 256;
  const uint4* keys = (const uint4*)((const char*)ws + B_KVPROJ);
  const uint4* vals = (const uint4*)((const char*)ws + B_QSM);
  #pragma unroll
  for (int it = 0; it < 4; ++it){
    int i = it*256 + t;                 // 0..1023
    int row = i >> 5, c8 = i & 31;      // 32 uint4 per 256-bf16 row slice
    size_t gi = ((((size_t)(h*32 + row)*8 + n)*L + l0) >> 3) + c8;
    uint4 ku = keys[gi], vu = vals[gi];
    float4 e0, e1, v0, v1;
    e0.x = __expf(__uint_as_float(ku.x << 16));
    e0.y = __expf(__uint_as_float(ku.x & 0xFFFF0000u));
    e0.z = __expf(__uint_as_float(ku.y << 16));
    e0.w = __expf(__uint_as_float(ku.y & 0xFFFF0000u));
    e1.x = __expf(__uint_as_float(ku.z << 16));
    e1.y = __expf(__uint_as_float(ku.z & 0xFFFF0000u));
    e1.z = __expf(__uint_as_float(ku.w << 16));
    e1.w = __expf(__uint_as_float(ku.w & 0xFFFF0000u));
    v0.x = __uint_as_float(vu.x << 16);
    v0.y = __uint_as_float(vu.x & 0xFFFF0000u);
    v0.z = __uint_as_float(vu.y << 16);
    v0.w = __uint_as_float(vu.y & 0xFFFF0000u);
    v1.x = __uint_as_float(vu.z << 16);
    v1.y = __uint_as_float(vu.z & 0xFFFF0000u);
    v1.z = __uint_as_float(vu.w << 16);
    v1.w = __uint_as_float(vu.w & 0xFFFF0000u);
    *(float4*)&eb[row][c8*8]     = e0;
    *(float4*)&eb[row][c8*8 + 4] = e1;
    *(float4*)&vb[row][c8*8]     = v0;
    *(float4*)&vb[row][c8*8 + 4] = v1;
  }
  __syncthreads();
  int k = t >> 3, vg = t & 7;
  float d0=0.f, c0=0.f, c1=0.f, c2a=0.f, c3=0.f;
  for (int p = 0; p < 256; p += 4){
    float4 e  = *(const float4*)&eb[k][p];
    float4 v0 = *(const float4*)&vb[vg     ][p];
    float4 v1 = *(const float4*)&vb[vg + 8 ][p];
    float4 v2 = *(const float4*)&vb[vg + 16][p];
    float4 v3 = *(const float4*)&vb[vg + 24][p];
    d0 += e.x + e.y + e.z + e.w;
    c0 = fmaf(e.x,v0.x,fmaf(e.y,v0.y,fmaf(e.z,v0.z,fmaf(e.w,v0.w,c0))));
    c1 = fmaf(e.x,v1.x,fmaf(e.y,v1.y,fmaf(e.z,v1.z,fmaf(e.w,v1.w,c1))));
    c2a= fmaf(e.x,v2.x,fmaf(e.y,v2.y,fmaf(e.z,v2.z,fmaf(e.w,v2.w,c2a))));
    c3 = fmaf(e.x,v3.x,fmaf(e.y,v3.y,fmaf(e.z,v3.z,fmaf(e.w,v3.w,c3))));
  }
  float* ctx = ws + F_CTX + (size_t)nh*1024 + k*32;
  atomicAdd(ctx + vg,      c0);
  atomicAdd(ctx + vg + 8,  c1);
  atomicAdd(ctx + vg + 16, c2a);
  atomicAdd(ctx + vg + 24, c3);
  if (vg == 0) atomicAdd(ws + F_DENOM + nh*32 + k, d0);
}

// ---------------- M2 = Wp x ctx_norm^T, bf16 pre-swizzled per n ------
__global__ __launch_bounds__(256) void k_m2(const float* __restrict__ Wp,
                                            float* __restrict__ ws)
{
  __shared__ float cn[32][33];
  int t = threadIdx.x, bx = blockIdx.x;
  int n = bx >> 3, h = bx & 7;
  int nh = bx;
  #pragma unroll
  for (int jj = 0; jj < 4; ++jj){
    int i = jj*256 + t;
    int k = i >> 5, v = i & 31;
    cn[k][v] = ws[F_CTX + (size_t)nh*1024 + i] / ws[F_DENOM + nh*32 + k];
  }
  __syncthreads();
  int c = t;
  const float* wrow = Wp + (size_t)c*256 + h*32;
  float w[32];
  #pragma unroll
  for (int v = 0; v < 32; ++v) w[v] = wrow[v];
  float s[32];
  #pragma unroll
  for (int k = 0; k < 32; ++k){
    float a = 0.f;
    #pragma unroll
    for (int v = 0; v < 32; ++v) a = fmaf(w[v], cn[k][v], a);
    s[k] = a;
  }
  char* base = (char*)ws + B_M2 + (size_t)n*131072;
  int opl = c >> 7, rl = c & 127, kc = h >> 1;
  #pragma unroll
  for (int gg = 0; gg < 4; ++gg){
    int g = (h & 1)*4 + gg;
    uint4 u = make_uint4(pack2(s[gg*8+0], s[gg*8+1]), pack2(s[gg*8+2], s[gg*8+3]),
                         pack2(s[gg*8+4], s[gg*8+5]), pack2(s[gg*8+6], s[gg*8+7]));
    *(uint4*)(base + (size_t)((opl*4 + kc)*1024 + rl*8 + (g ^ swz(rl)))*16) = u;
  }
}

extern "C" void kernel_launch(void* const* d_in, const int* in_sizes, int n_in,
                              void* d_out, int out_size, void* d_ws, size_t ws_size,
                              hipStream_t stream)
{
  const float* q_in = (const float*)d_in[0];
  const float* kv   = (const float*)d_in[1];
  const float* Wq   = (const float*)d_in[2];
  const float* Wk   = (const float*)d_in[3];
  const float* Wv   = (const float*)d_in[4];
  const float* Wp   = (const float*)d_in[5];
  const float* qg   = (const float*)d_in[6];
  const float* qb   = (const float*)d_in[7];
  const float* kg   = (const float*)d_in[8];
  const float* kb   = (const float*)d_in[9];
  float* out = (float*)d_out;
  float* wsf = (float*)d_ws;
  char*  outa = (char*)d_out;
  ushort* kvproj = (ushort*)((char*)d_ws + B_KVPROJ);
  ushort* qsm    = (ushort*)((char*)d_ws + B_QSM);
  const float* biasf = (const float*)(outa + O_BIAS);

  k_init <<<dim3(268),  dim3(256), 0, stream>>>(wsf);
  k_stats<<<dim3(2048), dim3(256), 0, stream>>>(q_in, kv, wsf);
  k_wfold<<<dim3(3),    dim3(256), 0, stream>>>(Wk, Wv, Wq, wsf, qg, qb, kg, kb, outa);
  k_gemm<0><<<dim3(72,4,8), dim3(256), 0, stream>>>(outa + O_WF, 0, kv,
      biasf, kvproj, nullptr, 8, 1);
  k_ctx  <<<dim3(2304), dim3(256), 0, stream>>>(wsf);
  k_m2   <<<dim3(64),   dim3(256), 0, stream>>>(Wp, wsf);
  k_gemm<1><<<dim3(72,2,8), dim3(256), 0, stream>>>(outa + O_WF + 262144, 0, q_in,
      biasf + 512, qsm, nullptr, 1, 256);
  k_gemm<2><<<dim3(72,2,8), dim3(256), 0, stream>>>((char*)d_ws + B_M2, 131072, qsm,
      nullptr, out, q_in, 1, 256);
}

// Round 6
// 207.674 us; speedup vs baseline: 31.0852x; 1.0388x over previous
//
#include <hip/hip_runtime.h>

#define L 9216
#define CNTF 73728.0f

// ws float-index offsets
#define F_DENOM 1024
#define F_CTX 3072
#define F_STATS 68608          // aliases B_M2 start (stats dead before k_m2 writes)
// ws byte offsets
#define B_M2 274432u           // per-n 128KB pre-swizzled bf16 M2 (8 MB)
#define B_QSM 38023168u        // qsm [8 n][256 hk][9216 l] bf16

// d_out byte aliases (dead until reproj finally overwrites everything)
#define O_WF 0u                // kv-interleaved image (256KB) then Wq' (128KB)
#define O_BIAS 393216u         // 768 f32: kv-interleaved bias[512], bq[256]

typedef float floatx4 __attribute__((ext_vector_type(4)));
typedef __bf16 bf16x8 __attribute__((ext_vector_type(8)));

__device__ __forceinline__ unsigned short f2bf(float f){
  return __builtin_bit_cast(unsigned short, (__bf16)f);   // RNE, compiler cvt
}
__device__ __forceinline__ unsigned pack2(float lo, float hi){
  return (unsigned)f2bf(lo) | ((unsigned)f2bf(hi) << 16); // -> v_cvt_pk_bf16_f32
}
__device__ __forceinline__ int swz(int r){ return (r ^ (r >> 4)) & 7; }
__device__ __forceinline__ int sw4(int r){ return (r ^ (r >> 4)) & 15; }

__device__ __forceinline__ void gload16(const void* g, void* l){
  __builtin_amdgcn_global_load_lds(
      (const __attribute__((address_space(1))) unsigned*)g,
      (__attribute__((address_space(3))) unsigned*)l, 16, 0, 0);
}

// ---------------- init: zero denom + ctx + stats accumulators --------
__global__ __launch_bounds__(256) void k_init(float* __restrict__ ws){
  int i = blockIdx.x * 256 + threadIdx.x;
  if (i < 68608) ws[F_DENOM + i] = 0.0f;
}

// ---------------- BN stats: one (tensor,n,c) row per block -----------
__global__ __launch_bounds__(256) void k_stats(const float* __restrict__ q,
                                               const float* __restrict__ kv,
                                               float* __restrict__ ws){
  int b = blockIdx.x, t = threadIdx.x;     // 4096 blocks
  int ten = b >> 11;
  int row = b & 2047;                      // n*256 + c
  int c = row & 255;
  const float4* p = (const float4*)((ten ? kv : q) + (size_t)row * L);
  float s = 0.f, ss = 0.f;
  #pragma unroll
  for (int j = 0; j < 9; ++j){
    float4 v = p[t + 256*j];
    s  += v.x + v.y + v.z + v.w;
    ss += v.x*v.x + v.y*v.y + v.z*v.z + v.w*v.w;
  }
  #pragma unroll
  for (int off = 1; off < 64; off <<= 1){
    s += __shfl_xor(s, off); ss += __shfl_xor(ss, off);
  }
  __shared__ float r4[2][4];
  int w = t >> 6;
  if ((t & 63) == 0){ r4[0][w] = s; r4[1][w] = ss; }
  __syncthreads();
  if (t == 0){
    s  = r4[0][0]+r4[0][1]+r4[0][2]+r4[0][3];
    ss = r4[1][0]+r4[1][1]+r4[1][2]+r4[1][3];
    atomicAdd(&ws[F_STATS + ten*512 + c], s);
    atomicAdd(&ws[F_STATS + ten*512 + 256 + c], ss);
  }
}

// -------- fold BN into weights (coef in-block); head-pair interleave --
// b=0: Wk, b=1: Wv -> one 256KB image; row h*32+i maps to
// imgrow = (h>>1)*128 + (h&1)*64 + (b==1)*32 + i.  b=2: Wq -> own image.
__global__ __launch_bounds__(256) void k_wfold(const float* __restrict__ W0,
    const float* __restrict__ W1, const float* __restrict__ W2,
    const float* __restrict__ ws,
    const float* __restrict__ qg, const float* __restrict__ qb,
    const float* __restrict__ kg, const float* __restrict__ kb,
    char* __restrict__ outa){
  __shared__ float sc[256], sh[256];
  int b = blockIdx.x, r = threadIdx.x;
  int tsel = (b < 2) ? 1 : 0;                 // Wk,Wv use kv stats; Wq uses q
  {
    float s  = ws[F_STATS + tsel*512 + r];
    float ssum = ws[F_STATS + tsel*512 + 256 + r];
    float m = s * (1.0f/CNTF);
    float vv = ssum * (1.0f/CNTF) - m*m;
    float g  = tsel ? kg[r] : qg[r];
    float be = tsel ? kb[r] : qb[r];
    float scv = rsqrtf(vv + 1e-3f) * g;
    sc[r] = scv; sh[r] = be - m*scv;
  }
  __syncthreads();
  const float* W = (b == 0) ? W0 : ((b == 1) ? W1 : W2);
  const float* wrow = W + (size_t)r * 256;
  int imgrow, biasidx;
  char* chunk;
  if (b < 2){
    int h = r >> 5;
    imgrow = (h >> 1)*128 + (h & 1)*64 + b*32 + (r & 31);
    biasidx = imgrow;
    chunk = outa + O_WF;
  } else {
    imgrow = r;
    biasidx = 512 + r;
    chunk = outa + O_WF + 262144;
  }
  int opl = imgrow >> 7, rl = imgrow & 127;
  float bias = 0.f;
  for (int kc = 0; kc < 4; ++kc){
    unsigned pk[8][4];
    #pragma unroll
    for (int g = 0; g < 8; ++g){
      float v[8];
      #pragma unroll
      for (int m = 0; m < 8; ++m){
        int k = kc*64 + g*8 + m;
        float w = wrow[k];
        v[m] = w * sc[k];
        bias = fmaf(w, sh[k], bias);
      }
      pk[g][0] = pack2(v[0], v[1]); pk[g][1] = pack2(v[2], v[3]);
      pk[g][2] = pack2(v[4], v[5]); pk[g][3] = pack2(v[6], v[7]);
    }
    #pragma unroll
    for (int g = 0; g < 8; ++g){
      int idx = (opl*4 + kc)*1024 + rl*8 + (g ^ swz(rl));
      *(uint4*)(chunk + (size_t)idx*16) =
          make_uint4(pk[g][0], pk[g][1], pk[g][2], pk[g][3]);
    }
  }
  ((float*)(outa + O_BIAS))[biasidx] = bias;
}

// ---- fused KV projection + exp + context/denominator accumulation ----
// grid (18 lpg, 4 op, 8 n); op chunk = heads {2op, 2op+1}:
// rows 0-31 keys_h0, 32-63 vals_h0, 64-95 keys_h1, 96-127 vals_h1.
// keys/vals never leave the chip: ctx += E_h x V_h^T via MFMA on LDS tile.
__global__ __launch_bounds__(256, 2) void k_fkv(
    const char* __restrict__ Af, const float* __restrict__ kv,
    const float* __restrict__ bias, float* __restrict__ ws)
{
  __shared__ __align__(16) ushort As[128*64];    // 16 KB swizzled
  __shared__ __align__(16) ushort Bs[128*64];    // 16 KB swizzled
  __shared__ __align__(16) ushort EV[128*128];   // 32 KB swizzled (sw4)
  const int t = threadIdx.x;
  const int lane = t & 63, wid = t >> 6;
  const int wr = wid >> 1, wc = wid & 1;
  const int lpg = blockIdx.x, op = blockIdx.y, n = blockIdx.z;
  const char* Achunk = Af + (size_t)op * 65536;
  const int cpair = t >> 3, lg = t & 7;
  const int lcol = lane & 15, lhi = lane >> 4;
  const int lrow4 = lhi * 4;

  floatx4 c16[2] = {};            // ctx acc: head wr, v-half wc, i0 = 0,1
  float dn[2][4] = {};            // denom acc: key rows mf 0,1 x r

  for (int lpi = 0; lpi < 4; ++lpi){
    const int l0 = (lpg*4 + lpi) * 128;
    floatx4 acc[4][4] = {};
    for (int kc = 0; kc < 4; ++kc){
      {
        const char* src = Achunk + kc*16384 + ((size_t)(wid*4*64 + lane))*16;
        ushort* dst = As + wid*4*512;
        gload16(src,        dst);
        gload16(src + 1024, dst + 512);
        gload16(src + 2048, dst + 1024);
        gload16(src + 3072, dst + 1536);
      }
      unsigned bu[16];
      {
        const float* Xa = kv + ((size_t)(n*256 + kc*64 + 2*cpair))*L + l0 + lg*16;
        const float* Xb = Xa + L;
        #pragma unroll
        for (int q = 0; q < 4; ++q){
          float4 a = ((const float4*)Xa)[q];
          float4 b = ((const float4*)Xb)[q];
          bu[4*q+0] = pack2(a.x, b.x);
          bu[4*q+1] = pack2(a.y, b.y);
          bu[4*q+2] = pack2(a.z, b.z);
          bu[4*q+3] = pack2(a.w, b.w);
        }
      }
      {
        int g = cpair >> 2, d = cpair & 3;
        #pragma unroll
        for (int j = 0; j < 16; ++j){
          int ll = lg*16 + j;
          *(unsigned*)((char*)Bs + ll*128 + ((g ^ swz(ll))*16) + d*4) = bu[j];
        }
      }
      __syncthreads();
      #pragma unroll
      for (int ks = 0; ks < 2; ++ks){
        bf16x8 af[4], bfr[4];
        #pragma unroll
        for (int mf = 0; mf < 4; ++mf){
          int row = wr*64 + mf*16 + lcol;
          int gq = (ks*4 + lhi) ^ swz(row);
          af[mf] = *(const bf16x8*)(As + row*64 + gq*8);
        }
        #pragma unroll
        for (int nf = 0; nf < 4; ++nf){
          int ll = wc*64 + nf*16 + lcol;
          int gq = (ks*4 + lhi) ^ swz(ll);
          bfr[nf] = *(const bf16x8*)(Bs + ll*64 + gq*8);
        }
        #pragma unroll
        for (int mf = 0; mf < 4; ++mf)
          #pragma unroll
          for (int nf = 0; nf < 4; ++nf)
            acc[mf][nf] = __builtin_amdgcn_mfma_f32_16x16x32_bf16(af[mf], bfr[nf], acc[mf][nf], 0, 0, 0);
      }
      __syncthreads();
    }

    // bias; exp for key rows (mf 0,1); accumulate denom partials
    #pragma unroll
    for (int mf = 0; mf < 4; ++mf)
      #pragma unroll
      for (int r = 0; r < 4; ++r){
        float bv = bias[op*128 + wr*64 + mf*16 + lrow4 + r];
        if (mf < 2){
          #pragma unroll
          for (int nf = 0; nf < 4; ++nf)
            acc[mf][nf][r] = __expf(acc[mf][nf][r] + bv);
        } else {
          #pragma unroll
          for (int nf = 0; nf < 4; ++nf)
            acc[mf][nf][r] += bv;
        }
      }
    #pragma unroll
    for (int mf = 0; mf < 2; ++mf)
      #pragma unroll
      for (int r = 0; r < 4; ++r){
        float s = acc[mf][0][r] + acc[mf][1][r] + acc[mf][2][r] + acc[mf][3][r];
        s += __shfl_xor(s, 1); s += __shfl_xor(s, 2);
        s += __shfl_xor(s, 4); s += __shfl_xor(s, 8);
        dn[mf][r] += s;
      }
    // scatter E/V tile to swizzled LDS (bf16)
    #pragma unroll
    for (int mf = 0; mf < 4; ++mf)
      #pragma unroll
      for (int nf = 0; nf < 4; ++nf)
        #pragma unroll
        for (int r = 0; r < 4; ++r){
          int row = wr*64 + mf*16 + lrow4 + r;
          int col = wc*64 + nf*16 + lcol;
          int g = (col >> 3) ^ sw4(row);
          *(ushort*)((char*)EV + row*256 + g*16 + (col & 7)*2) = f2bf(acc[mf][nf][r]);
        }
    __syncthreads();
    // ctx += E (32 x 128) x V^T (128 x 32) for head wr, v-half wc
    #pragma unroll
    for (int kk = 0; kk < 4; ++kk){
      int k0 = kk*32 + lhi*8;
      int gk = k0 >> 3;
      bf16x8 aE0, aE1, bV;
      {
        int row = wr*64 + lcol;
        aE0 = *(const bf16x8*)((const char*)EV + row*256 + ((gk ^ sw4(row))*16));
      }
      {
        int row = wr*64 + 16 + lcol;
        aE1 = *(const bf16x8*)((const char*)EV + row*256 + ((gk ^ sw4(row))*16));
      }
      {
        int row = wr*64 + 32 + wc*16 + lcol;
        bV = *(const bf16x8*)((const char*)EV + row*256 + ((gk ^ sw4(row))*16));
      }
      c16[0] = __builtin_amdgcn_mfma_f32_16x16x32_bf16(aE0, bV, c16[0], 0, 0, 0);
      c16[1] = __builtin_amdgcn_mfma_f32_16x16x32_bf16(aE1, bV, c16[1], 0, 0, 0);
    }
    // next lpi's EV writes happen only after its 4 kc barriers -> reads safe
  }

  float* ctxp = ws + F_CTX + (size_t)((n*8) + op*2 + wr)*1024;
  #pragma unroll
  for (int i0 = 0; i0 < 2; ++i0)
    #pragma unroll
    for (int r = 0; r < 4; ++r)
      atomicAdd(ctxp + (i0*16 + lrow4 + r)*32 + wc*16 + lcol, c16[i0][r]);
  if (lcol == 0){
    float* dnp = ws + F_DENOM + (size_t)((n*8) + op*2 + wr)*32;
    #pragma unroll
    for (int mf = 0; mf < 2; ++mf)
      #pragma unroll
      for (int r = 0; r < 4; ++r)
        atomicAdd(dnp + mf*16 + lrow4 + r, dn[mf][r]);
  }
}

// ---------------- MFMA GEMM: 128x128 tile, A via global_load_lds -----
// MODE 1: bias + softmax-over-32-rows epilogue, bf16 out (qsm).
// MODE 2: B bf16 (qsm), f32 out + residual.
template<int MODE>
__global__ __launch_bounds__(256, 3) void k_gemm(
    const char* __restrict__ Af, size_t a_nstride,
    const void* __restrict__ Bsrc,
    const float* __restrict__ bias,
    void* __restrict__ outp, const float* __restrict__ xres,
    int ors, int ons)
{
  __shared__ __align__(16) ushort As[128*64];
  __shared__ __align__(16) ushort Bs[128*64];
  const int t = threadIdx.x;
  const int lane = t & 63, wid = t >> 6;
  const int wr = wid >> 1, wc = wid & 1;
  const int lp = blockIdx.x, op = blockIdx.y, n = blockIdx.z;
  const int l0 = lp * 128, o0 = op * 128;
  const char* Achunk = Af + (size_t)n * a_nstride + (size_t)op * 65536;

  const int cpair = t >> 3, lg = t & 7;
  const int lcol = lane & 15, lhi = lane >> 4;

  floatx4 acc[4][4] = {};

  for (int kc = 0; kc < 4; ++kc) {
    {
      const char* src = Achunk + kc*16384 + ((size_t)(wid*4*64 + lane))*16;
      ushort* dst = As + wid*4*512;
      gload16(src,        dst);
      gload16(src + 1024, dst + 512);
      gload16(src + 2048, dst + 1024);
      gload16(src + 3072, dst + 1536);
    }
    unsigned bu[16];
    if (MODE == 2) {
      const ushort* X = (const ushort*)Bsrc + ((size_t)(n*256 + kc*64 + 2*cpair))*L + l0 + lg*16;
      uint4 ra  = *(const uint4*)X;
      uint4 ra2 = *(const uint4*)(X + 8);
      uint4 rb  = *(const uint4*)(X + L);
      uint4 rb2 = *(const uint4*)(X + L + 8);
      bu[0] = (ra.x & 0xFFFFu) | (rb.x << 16);  bu[1] = (ra.x >> 16) | (rb.x & 0xFFFF0000u);
      bu[2] = (ra.y & 0xFFFFu) | (rb.y << 16);  bu[3] = (ra.y >> 16) | (rb.y & 0xFFFF0000u);
      bu[4] = (ra.z & 0xFFFFu) | (rb.z << 16);  bu[5] = (ra.z >> 16) | (rb.z & 0xFFFF0000u);
      bu[6] = (ra.w & 0xFFFFu) | (rb.w << 16);  bu[7] = (ra.w >> 16) | (rb.w & 0xFFFF0000u);
      bu[8]  = (ra2.x & 0xFFFFu) | (rb2.x << 16); bu[9]  = (ra2.x >> 16) | (rb2.x & 0xFFFF0000u);
      bu[10] = (ra2.y & 0xFFFFu) | (rb2.y << 16); bu[11] = (ra2.y >> 16) | (rb2.y & 0xFFFF0000u);
      bu[12] = (ra2.z & 0xFFFFu) | (rb2.z << 16); bu[13] = (ra2.z >> 16) | (rb2.z & 0xFFFF0000u);
      bu[14] = (ra2.w & 0xFFFFu) | (rb2.w << 16); bu[15] = (ra2.w >> 16) | (rb2.w & 0xFFFF0000u);
    } else {
      const float* Xa = (const float*)Bsrc + ((size_t)(n*256 + kc*64 + 2*cpair))*L + l0 + lg*16;
      const float* Xb = Xa + L;
      #pragma unroll
      for (int q = 0; q < 4; ++q) {
        float4 a = ((const float4*)Xa)[q];
        float4 b = ((const float4*)Xb)[q];
        bu[4*q+0] = pack2(a.x, b.x);
        bu[4*q+1] = pack2(a.y, b.y);
        bu[4*q+2] = pack2(a.z, b.z);
        bu[4*q+3] = pack2(a.w, b.w);
      }
    }
    {
      int g = cpair >> 2, d = cpair & 3;
      #pragma unroll
      for (int j = 0; j < 16; ++j){
        int ll = lg*16 + j;
        *(unsigned*)((char*)Bs + ll*128 + ((g ^ swz(ll))*16) + d*4) = bu[j];
      }
    }
    __syncthreads();
    #pragma unroll
    for (int ks = 0; ks < 2; ++ks) {
      bf16x8 af[4], bfr[4];
      #pragma unroll
      for (int mf = 0; mf < 4; ++mf) {
        int row = wr*64 + mf*16 + lcol;
        int gq = (ks*4 + lhi) ^ swz(row);
        af[mf] = *(const bf16x8*)(As + row*64 + gq*8);
      }
      #pragma unroll
      for (int nf = 0; nf < 4; ++nf) {
        int ll = wc*64 + nf*16 + lcol;
        int gq = (ks*4 + lhi) ^ swz(ll);
        bfr[nf] = *(const bf16x8*)(Bs + ll*64 + gq*8);
      }
      #pragma unroll
      for (int mf = 0; mf < 4; ++mf)
        #pragma unroll
        for (int nf = 0; nf < 4; ++nf)
          acc[mf][nf] = __builtin_amdgcn_mfma_f32_16x16x32_bf16(af[mf], bfr[nf], acc[mf][nf], 0, 0, 0);
    }
    __syncthreads();
  }

  const int lrow4 = lhi * 4;

  if (MODE == 1) {
    #pragma unroll
    for (int mf = 0; mf < 4; ++mf)
      #pragma unroll
      for (int r = 0; r < 4; ++r) {
        float bv = bias[o0 + wr*64 + mf*16 + lrow4 + r];
        #pragma unroll
        for (int nf = 0; nf < 4; ++nf)
          acc[mf][nf][r] = __expf(acc[mf][nf][r] + bv);
      }
    #pragma unroll
    for (int hg = 0; hg < 2; ++hg) {
      #pragma unroll
      for (int nf = 0; nf < 4; ++nf) {
        float s = 0.f;
        #pragma unroll
        for (int mh = 0; mh < 2; ++mh)
          #pragma unroll
          for (int r = 0; r < 4; ++r)
            s += acc[hg*2+mh][nf][r];
        s += __shfl_xor(s, 16);
        s += __shfl_xor(s, 32);
        float inv = 1.0f / s;
        #pragma unroll
        for (int mh = 0; mh < 2; ++mh)
          #pragma unroll
          for (int r = 0; r < 4; ++r)
            acc[hg*2+mh][nf][r] *= inv;
      }
    }
  }

  if (MODE == 2) {
    float* outf = (float*)outp;
    #pragma unroll
    for (int mf = 0; mf < 4; ++mf)
      #pragma unroll
      for (int r = 0; r < 4; ++r) {
        int orow = o0 + wr*64 + mf*16 + lrow4 + r;
        size_t base = ((size_t)n*256 + orow)*L + l0 + wc*64 + lcol;
        #pragma unroll
        for (int nf = 0; nf < 4; ++nf) {
          size_t gi = base + (size_t)nf*16;
          outf[gi] = acc[mf][nf][r] + xres[gi];
        }
      }
  } else {
    ushort* outb = (ushort*)outp;
    #pragma unroll
    for (int mf = 0; mf < 4; ++mf)
      #pragma unroll
      for (int r = 0; r < 4; ++r) {
        int orow = o0 + wr*64 + mf*16 + lrow4 + r;
        size_t base = ((size_t)orow*ors + (size_t)n*ons)*L + l0 + wc*64 + lcol;
        #pragma unroll
        for (int nf = 0; nf < 4; ++nf)
          outb[base + (size_t)nf*16] = f2bf(acc[mf][nf][r]);
      }
  }
}

// ---------------- M2 = Wp x ctx_norm^T, bf16 pre-swizzled per n ------
__global__ __launch_bounds__(256) void k_m2(const float* __restrict__ Wp,
                                            float* __restrict__ ws)
{
  __shared__ float cn[32][33];
  int t = threadIdx.x, bx = blockIdx.x;
  int n = bx >> 3, h = bx & 7;
  int nh = bx;
  #pragma unroll
  for (int jj = 0; jj < 4; ++jj){
    int i = jj*256 + t;
    int k = i >> 5, v = i & 31;
    cn[k][v] = ws[F_CTX + (size_t)nh*1024 + i] / ws[F_DENOM + nh*32 + k];
  }
  __syncthreads();
  int c = t;
  const float* wrow = Wp + (size_t)c*256 + h*32;
  float w[32];
  #pragma unroll
  for (int v = 0; v < 32; ++v) w[v] = wrow[v];
  float s[32];
  #pragma unroll
  for (int k = 0; k < 32; ++k){
    float a = 0.f;
    #pragma unroll
    for (int v = 0; v < 32; ++v) a = fmaf(w[v], cn[k][v], a);
    s[k] = a;
  }
  char* base = (char*)ws + B_M2 + (size_t)n*131072;
  int opl = c >> 7, rl = c & 127, kc = h >> 1;
  #pragma unroll
  for (int gg = 0; gg < 4; ++gg){
    int g = (h & 1)*4 + gg;
    uint4 u = make_uint4(pack2(s[gg*8+0], s[gg*8+1]), pack2(s[gg*8+2], s[gg*8+3]),
                         pack2(s[gg*8+4], s[gg*8+5]), pack2(s[gg*8+6], s[gg*8+7]));
    *(uint4*)(base + (size_t)((opl*4 + kc)*1024 + rl*8 + (g ^ swz(rl)))*16) = u;
  }
}

extern "C" void kernel_launch(void* const* d_in, const int* in_sizes, int n_in,
                              void* d_out, int out_size, void* d_ws, size_t ws_size,
                              hipStream_t stream)
{
  const float* q_in = (const float*)d_in[0];
  const float* kv   = (const float*)d_in[1];
  const float* Wq   = (const float*)d_in[2];
  const float* Wk   = (const float*)d_in[3];
  const float* Wv   = (const float*)d_in[4];
  const float* Wp   = (const float*)d_in[5];
  const float* qg   = (const float*)d_in[6];
  const float* qb   = (const float*)d_in[7];
  const float* kg   = (const float*)d_in[8];
  const float* kb   = (const float*)d_in[9];
  float* out = (float*)d_out;
  float* wsf = (float*)d_ws;
  char*  outa = (char*)d_out;
  ushort* qsm = (ushort*)((char*)d_ws + B_QSM);
  const float* biasf = (const float*)(outa + O_BIAS);

  k_init <<<dim3(268),  dim3(256), 0, stream>>>(wsf);
  k_stats<<<dim3(4096), dim3(256), 0, stream>>>(q_in, kv, wsf);
  k_wfold<<<dim3(3),    dim3(256), 0, stream>>>(Wk, Wv, Wq, wsf, qg, qb, kg, kb, outa);
  k_fkv  <<<dim3(18,4,8), dim3(256), 0, stream>>>(outa + O_WF, kv, biasf, wsf);
  k_m2   <<<dim3(64),   dim3(256), 0, stream>>>(Wp, wsf);
  k_gemm<1><<<dim3(72,2,8), dim3(256), 0, stream>>>(outa + O_WF + 262144, 0, q_in,
      biasf + 512, qsm, nullptr, 1, 256);
  k_gemm<2><<<dim3(72,2,8), dim3(256), 0, stream>>>((char*)d_ws + B_M2, 131072, qsm,
      nullptr, out, q_in, 1, 256);
}

// Round 7
// 198.598 us; speedup vs baseline: 32.5059x; 1.0457x over previous
//
#include <hip/hip_runtime.h>

#define L 9216
#define CNTF 73728.0f

// ws float-index offsets
#define F_DENOM 1024
#define F_CTX 3072
#define F_STATS 68608          // aliases B_M2 start (stats dead before k_m2 writes)
// ws byte offsets
#define B_M2 274432u           // per-n 128KB pre-swizzled bf16 M2 (8 MB)
#define B_QSM 38023168u        // qsm [8 n][256 hk][9216 l] bf16

// d_out byte aliases (dead until reproj finally overwrites everything)
#define O_WF 0u                // kv-interleaved image (256KB) then Wq' (128KB)
#define O_BIAS 393216u         // 768 f32: kv-interleaved bias[512], bq[256]

typedef float floatx4 __attribute__((ext_vector_type(4)));
typedef __bf16 bf16x8 __attribute__((ext_vector_type(8)));

__device__ __forceinline__ unsigned short f2bf(float f){
  return __builtin_bit_cast(unsigned short, (__bf16)f);   // RNE, compiler cvt
}
__device__ __forceinline__ unsigned pack2(float lo, float hi){
  return (unsigned)f2bf(lo) | ((unsigned)f2bf(hi) << 16); // -> v_cvt_pk_bf16_f32
}
__device__ __forceinline__ int swz(int r){ return (r ^ (r >> 4)) & 7; }
__device__ __forceinline__ int sw4(int r){ return (r ^ (r >> 4)) & 15; }

__device__ __forceinline__ void gload16(const void* g, void* l){
  __builtin_amdgcn_global_load_lds(
      (const __attribute__((address_space(1))) unsigned*)g,
      (__attribute__((address_space(3))) unsigned*)l, 16, 0, 0);
}

// ---------------- init: zero denom + ctx + stats accumulators --------
__global__ __launch_bounds__(256) void k_init(float* __restrict__ ws){
  int i = blockIdx.x * 256 + threadIdx.x;
  if (i < 68608) ws[F_DENOM + i] = 0.0f;
}

// ------- BN stats: 9 in-flight float4 loads (VGPR budget via LB) ------
__global__ __launch_bounds__(256, 4) void k_stats(const float* __restrict__ q,
                                                  const float* __restrict__ kv,
                                                  float* __restrict__ ws){
  int b = blockIdx.x, t = threadIdx.x;     // 4096 blocks, one (ten,n,c) row each
  int ten = b >> 11;
  int row = b & 2047;                      // n*256 + c
  int c = row & 255;
  const float4* p = (const float4*)((ten ? kv : q) + (size_t)row * L);
  float4 v0 = p[t        ], v1 = p[t +  256], v2 = p[t +  512];
  float4 v3 = p[t +  768 ], v4 = p[t + 1024], v5 = p[t + 1280];
  float4 v6 = p[t + 1536 ], v7 = p[t + 1792], v8 = p[t + 2048];
  float s0 = v0.x+v0.y+v0.z+v0.w, q0 = v0.x*v0.x+v0.y*v0.y+v0.z*v0.z+v0.w*v0.w;
  float s1 = v1.x+v1.y+v1.z+v1.w, q1 = v1.x*v1.x+v1.y*v1.y+v1.z*v1.z+v1.w*v1.w;
  float s2 = v2.x+v2.y+v2.z+v2.w, q2 = v2.x*v2.x+v2.y*v2.y+v2.z*v2.z+v2.w*v2.w;
  s0 += v3.x+v3.y+v3.z+v3.w; q0 += v3.x*v3.x+v3.y*v3.y+v3.z*v3.z+v3.w*v3.w;
  s1 += v4.x+v4.y+v4.z+v4.w; q1 += v4.x*v4.x+v4.y*v4.y+v4.z*v4.z+v4.w*v4.w;
  s2 += v5.x+v5.y+v5.z+v5.w; q2 += v5.x*v5.x+v5.y*v5.y+v5.z*v5.z+v5.w*v5.w;
  s0 += v6.x+v6.y+v6.z+v6.w; q0 += v6.x*v6.x+v6.y*v6.y+v6.z*v6.z+v6.w*v6.w;
  s1 += v7.x+v7.y+v7.z+v7.w; q1 += v7.x*v7.x+v7.y*v7.y+v7.z*v7.z+v7.w*v7.w;
  s2 += v8.x+v8.y+v8.z+v8.w; q2 += v8.x*v8.x+v8.y*v8.y+v8.z*v8.z+v8.w*v8.w;
  float s = s0 + s1 + s2, ss = q0 + q1 + q2;
  #pragma unroll
  for (int off = 1; off < 64; off <<= 1){
    s += __shfl_xor(s, off); ss += __shfl_xor(ss, off);
  }
  __shared__ float r4[2][4];
  int w = t >> 6;
  if ((t & 63) == 0){ r4[0][w] = s; r4[1][w] = ss; }
  __syncthreads();
  if (t == 0){
    s  = r4[0][0]+r4[0][1]+r4[0][2]+r4[0][3];
    ss = r4[1][0]+r4[1][1]+r4[1][2]+r4[1][3];
    atomicAdd(&ws[F_STATS + ten*512 + c], s);
    atomicAdd(&ws[F_STATS + ten*512 + 256 + c], ss);
  }
}

// -------- fold BN into weights (coef in-block); head-pair interleave --
__global__ __launch_bounds__(256) void k_wfold(const float* __restrict__ W0,
    const float* __restrict__ W1, const float* __restrict__ W2,
    const float* __restrict__ ws,
    const float* __restrict__ qg, const float* __restrict__ qb,
    const float* __restrict__ kg, const float* __restrict__ kb,
    char* __restrict__ outa){
  __shared__ float sc[256], sh[256];
  int b = blockIdx.x, r = threadIdx.x;
  int tsel = (b < 2) ? 1 : 0;                 // Wk,Wv use kv stats; Wq uses q
  {
    float s  = ws[F_STATS + tsel*512 + r];
    float ssum = ws[F_STATS + tsel*512 + 256 + r];
    float m = s * (1.0f/CNTF);
    float vv = ssum * (1.0f/CNTF) - m*m;
    float g  = tsel ? kg[r] : qg[r];
    float be = tsel ? kb[r] : qb[r];
    float scv = rsqrtf(vv + 1e-3f) * g;
    sc[r] = scv; sh[r] = be - m*scv;
  }
  __syncthreads();
  const float* W = (b == 0) ? W0 : ((b == 1) ? W1 : W2);
  const float* wrow = W + (size_t)r * 256;
  int imgrow, biasidx;
  char* chunk;
  if (b < 2){
    int h = r >> 5;
    imgrow = (h >> 1)*128 + (h & 1)*64 + b*32 + (r & 31);
    biasidx = imgrow;
    chunk = outa + O_WF;
  } else {
    imgrow = r;
    biasidx = 512 + r;
    chunk = outa + O_WF + 262144;
  }
  int opl = imgrow >> 7, rl = imgrow & 127;
  float bias = 0.f;
  for (int kc = 0; kc < 4; ++kc){
    unsigned pk[8][4];
    #pragma unroll
    for (int g = 0; g < 8; ++g){
      float v[8];
      #pragma unroll
      for (int m = 0; m < 8; ++m){
        int k = kc*64 + g*8 + m;
        float w = wrow[k];
        v[m] = w * sc[k];
        bias = fmaf(w, sh[k], bias);
      }
      pk[g][0] = pack2(v[0], v[1]); pk[g][1] = pack2(v[2], v[3]);
      pk[g][2] = pack2(v[4], v[5]); pk[g][3] = pack2(v[6], v[7]);
    }
    #pragma unroll
    for (int g = 0; g < 8; ++g){
      int idx = (opl*4 + kc)*1024 + rl*8 + (g ^ swz(rl));
      *(uint4*)(chunk + (size_t)idx*16) =
          make_uint4(pk[g][0], pk[g][1], pk[g][2], pk[g][3]);
    }
  }
  ((float*)(outa + O_BIAS))[biasidx] = bias;
}

// ---- fused KV projection + exp + context/denominator accumulation ----
// XCD-grouped 1-D grid (576): xcd=bid&7, seq=bid>>3, op=seq&3 (fastest,
// same-XCD L2 reuse of the kv strip), gid=xcd*18+(seq>>2) -> (lpg,n).
__global__ __launch_bounds__(256, 2) void k_fkv(
    const char* __restrict__ Af, const float* __restrict__ kv,
    const float* __restrict__ bias, float* __restrict__ ws)
{
  __shared__ __align__(16) ushort As[128*64];    // 16 KB swizzled
  __shared__ __align__(16) ushort Bs[128*64];    // 16 KB swizzled
  __shared__ __align__(16) ushort EV[128*128];   // 32 KB swizzled (sw4)
  const int t = threadIdx.x;
  const int lane = t & 63, wid = t >> 6;
  const int wr = wid >> 1, wc = wid & 1;
  const int bid = blockIdx.x;
  const int xcd = bid & 7, seq = bid >> 3;
  const int op = seq & 3;
  const int gid = xcd * 18 + (seq >> 2);
  const int lpg = gid % 18, n = gid / 18;
  const char* Achunk = Af + (size_t)op * 65536;
  const int cpair = t >> 3, lg = t & 7;
  const int lcol = lane & 15, lhi = lane >> 4;
  const int lrow4 = lhi * 4;

  floatx4 c16[2] = {};            // ctx acc: head wr, v-half wc, i0 = 0,1
  float dn[2][4] = {};            // denom acc: key rows mf 0,1 x r

  for (int lpi = 0; lpi < 4; ++lpi){
    const int l0 = (lpg*4 + lpi) * 128;
    floatx4 acc[4][4] = {};
    for (int kc = 0; kc < 4; ++kc){
      {
        const char* src = Achunk + kc*16384 + ((size_t)(wid*4*64 + lane))*16;
        ushort* dst = As + wid*4*512;
        gload16(src,        dst);
        gload16(src + 1024, dst + 512);
        gload16(src + 2048, dst + 1024);
        gload16(src + 3072, dst + 1536);
      }
      unsigned bu[16];
      {
        const float* Xa = kv + ((size_t)(n*256 + kc*64 + 2*cpair))*L + l0 + lg*16;
        const float* Xb = Xa + L;
        #pragma unroll
        for (int q = 0; q < 4; ++q){
          float4 a = ((const float4*)Xa)[q];
          float4 b = ((const float4*)Xb)[q];
          bu[4*q+0] = pack2(a.x, b.x);
          bu[4*q+1] = pack2(a.y, b.y);
          bu[4*q+2] = pack2(a.z, b.z);
          bu[4*q+3] = pack2(a.w, b.w);
        }
      }
      {
        int g = cpair >> 2, d = cpair & 3;
        #pragma unroll
        for (int j = 0; j < 16; ++j){
          int ll = lg*16 + j;
          *(unsigned*)((char*)Bs + ll*128 + ((g ^ swz(ll))*16) + d*4) = bu[j];
        }
      }
      __syncthreads();
      #pragma unroll
      for (int ks = 0; ks < 2; ++ks){
        bf16x8 af[4], bfr[4];
        #pragma unroll
        for (int mf = 0; mf < 4; ++mf){
          int row = wr*64 + mf*16 + lcol;
          int gq = (ks*4 + lhi) ^ swz(row);
          af[mf] = *(const bf16x8*)(As + row*64 + gq*8);
        }
        #pragma unroll
        for (int nf = 0; nf < 4; ++nf){
          int ll = wc*64 + nf*16 + lcol;
          int gq = (ks*4 + lhi) ^ swz(ll);
          bfr[nf] = *(const bf16x8*)(Bs + ll*64 + gq*8);
        }
        #pragma unroll
        for (int mf = 0; mf < 4; ++mf)
          #pragma unroll
          for (int nf = 0; nf < 4; ++nf)
            acc[mf][nf] = __builtin_amdgcn_mfma_f32_16x16x32_bf16(af[mf], bfr[nf], acc[mf][nf], 0, 0, 0);
      }
      __syncthreads();
    }

    // bias; exp for key rows (mf 0,1); accumulate denom partials
    #pragma unroll
    for (int mf = 0; mf < 4; ++mf)
      #pragma unroll
      for (int r = 0; r < 4; ++r){
        float bv = bias[op*128 + wr*64 + mf*16 + lrow4 + r];
        if (mf < 2){
          #pragma unroll
          for (int nf = 0; nf < 4; ++nf)
            acc[mf][nf][r] = __expf(acc[mf][nf][r] + bv);
        } else {
          #pragma unroll
          for (int nf = 0; nf < 4; ++nf)
            acc[mf][nf][r] += bv;
        }
      }
    #pragma unroll
    for (int mf = 0; mf < 2; ++mf)
      #pragma unroll
      for (int r = 0; r < 4; ++r){
        float s = acc[mf][0][r] + acc[mf][1][r] + acc[mf][2][r] + acc[mf][3][r];
        s += __shfl_xor(s, 1); s += __shfl_xor(s, 2);
        s += __shfl_xor(s, 4); s += __shfl_xor(s, 8);
        dn[mf][r] += s;
      }
    // scatter E/V tile to swizzled LDS (bf16)
    #pragma unroll
    for (int mf = 0; mf < 4; ++mf)
      #pragma unroll
      for (int nf = 0; nf < 4; ++nf)
        #pragma unroll
        for (int r = 0; r < 4; ++r){
          int row = wr*64 + mf*16 + lrow4 + r;
          int col = wc*64 + nf*16 + lcol;
          int g = (col >> 3) ^ sw4(row);
          *(ushort*)((char*)EV + row*256 + g*16 + (col & 7)*2) = f2bf(acc[mf][nf][r]);
        }
    __syncthreads();
    // ctx += E (32 x 128) x V^T (128 x 32) for head wr, v-half wc
    #pragma unroll
    for (int kk = 0; kk < 4; ++kk){
      int k0 = kk*32 + lhi*8;
      int gk = k0 >> 3;
      bf16x8 aE0, aE1, bV;
      {
        int row = wr*64 + lcol;
        aE0 = *(const bf16x8*)((const char*)EV + row*256 + ((gk ^ sw4(row))*16));
      }
      {
        int row = wr*64 + 16 + lcol;
        aE1 = *(const bf16x8*)((const char*)EV + row*256 + ((gk ^ sw4(row))*16));
      }
      {
        int row = wr*64 + 32 + wc*16 + lcol;
        bV = *(const bf16x8*)((const char*)EV + row*256 + ((gk ^ sw4(row))*16));
      }
      c16[0] = __builtin_amdgcn_mfma_f32_16x16x32_bf16(aE0, bV, c16[0], 0, 0, 0);
      c16[1] = __builtin_amdgcn_mfma_f32_16x16x32_bf16(aE1, bV, c16[1], 0, 0, 0);
    }
  }

  float* ctxp = ws + F_CTX + (size_t)((n*8) + op*2 + wr)*1024;
  #pragma unroll
  for (int i0 = 0; i0 < 2; ++i0)
    #pragma unroll
    for (int r = 0; r < 4; ++r)
      atomicAdd(ctxp + (i0*16 + lrow4 + r)*32 + wc*16 + lcol, c16[i0][r]);
  if (lcol == 0){
    float* dnp = ws + F_DENOM + (size_t)((n*8) + op*2 + wr)*32;
    #pragma unroll
    for (int mf = 0; mf < 2; ++mf)
      #pragma unroll
      for (int r = 0; r < 4; ++r)
        atomicAdd(dnp + mf*16 + lrow4 + r, dn[mf][r]);
  }
}

// ---------------- MFMA GEMM: 128x128 tile, A via global_load_lds -----
// XCD-grouped 1-D grid (1152): op=seq&1 fastest -> same-XCD B reuse.
// MODE 1: bias + softmax-over-32-rows epilogue, bf16 out (qsm).
// MODE 2: B bf16 (qsm), f32 out + residual.
template<int MODE>
__global__ __launch_bounds__(256, 3) void k_gemm(
    const char* __restrict__ Af, size_t a_nstride,
    const void* __restrict__ Bsrc,
    const float* __restrict__ bias,
    void* __restrict__ outp, const float* __restrict__ xres,
    int ors, int ons)
{
  __shared__ __align__(16) ushort As[128*64];
  __shared__ __align__(16) ushort Bs[128*64];
  const int t = threadIdx.x;
  const int lane = t & 63, wid = t >> 6;
  const int wr = wid >> 1, wc = wid & 1;
  const int bid = blockIdx.x;
  const int xcd = bid & 7, seq = bid >> 3;
  const int op = seq & 1;
  const int gid = xcd * 72 + (seq >> 1);
  const int lp = gid % 72, n = gid / 72;
  const int l0 = lp * 128, o0 = op * 128;
  const char* Achunk = Af + (size_t)n * a_nstride + (size_t)op * 65536;

  const int cpair = t >> 3, lg = t & 7;
  const int lcol = lane & 15, lhi = lane >> 4;

  floatx4 acc[4][4] = {};

  for (int kc = 0; kc < 4; ++kc) {
    {
      const char* src = Achunk + kc*16384 + ((size_t)(wid*4*64 + lane))*16;
      ushort* dst = As + wid*4*512;
      gload16(src,        dst);
      gload16(src + 1024, dst + 512);
      gload16(src + 2048, dst + 1024);
      gload16(src + 3072, dst + 1536);
    }
    unsigned bu[16];
    if (MODE == 2) {
      const ushort* X = (const ushort*)Bsrc + ((size_t)(n*256 + kc*64 + 2*cpair))*L + l0 + lg*16;
      uint4 ra  = *(const uint4*)X;
      uint4 ra2 = *(const uint4*)(X + 8);
      uint4 rb  = *(const uint4*)(X + L);
      uint4 rb2 = *(const uint4*)(X + L + 8);
      bu[0] = (ra.x & 0xFFFFu) | (rb.x << 16);  bu[1] = (ra.x >> 16) | (rb.x & 0xFFFF0000u);
      bu[2] = (ra.y & 0xFFFFu) | (rb.y << 16);  bu[3] = (ra.y >> 16) | (rb.y & 0xFFFF0000u);
      bu[4] = (ra.z & 0xFFFFu) | (rb.z << 16);  bu[5] = (ra.z >> 16) | (rb.z & 0xFFFF0000u);
      bu[6] = (ra.w & 0xFFFFu) | (rb.w << 16);  bu[7] = (ra.w >> 16) | (rb.w & 0xFFFF0000u);
      bu[8]  = (ra2.x & 0xFFFFu) | (rb2.x << 16); bu[9]  = (ra2.x >> 16) | (rb2.x & 0xFFFF0000u);
      bu[10] = (ra2.y & 0xFFFFu) | (rb2.y << 16); bu[11] = (ra2.y >> 16) | (rb2.y & 0xFFFF0000u);
      bu[12] = (ra2.z & 0xFFFFu) | (rb2.z << 16); bu[13] = (ra2.z >> 16) | (rb2.z & 0xFFFF0000u);
      bu[14] = (ra2.w & 0xFFFFu) | (rb2.w << 16); bu[15] = (ra2.w >> 16) | (rb2.w & 0xFFFF0000u);
    } else {
      const float* Xa = (const float*)Bsrc + ((size_t)(n*256 + kc*64 + 2*cpair))*L + l0 + lg*16;
      const float* Xb = Xa + L;
      #pragma unroll
      for (int q = 0; q < 4; ++q) {
        float4 a = ((const float4*)Xa)[q];
        float4 b = ((const float4*)Xb)[q];
        bu[4*q+0] = pack2(a.x, b.x);
        bu[4*q+1] = pack2(a.y, b.y);
        bu[4*q+2] = pack2(a.z, b.z);
        bu[4*q+3] = pack2(a.w, b.w);
      }
    }
    {
      int g = cpair >> 2, d = cpair & 3;
      #pragma unroll
      for (int j = 0; j < 16; ++j){
        int ll = lg*16 + j;
        *(unsigned*)((char*)Bs + ll*128 + ((g ^ swz(ll))*16) + d*4) = bu[j];
      }
    }
    __syncthreads();
    #pragma unroll
    for (int ks = 0; ks < 2; ++ks) {
      bf16x8 af[4], bfr[4];
      #pragma unroll
      for (int mf = 0; mf < 4; ++mf) {
        int row = wr*64 + mf*16 + lcol;
        int gq = (ks*4 + lhi) ^ swz(row);
        af[mf] = *(const bf16x8*)(As + row*64 + gq*8);
      }
      #pragma unroll
      for (int nf = 0; nf < 4; ++nf) {
        int ll = wc*64 + nf*16 + lcol;
        int gq = (ks*4 + lhi) ^ swz(ll);
        bfr[nf] = *(const bf16x8*)(Bs + ll*64 + gq*8);
      }
      #pragma unroll
      for (int mf = 0; mf < 4; ++mf)
        #pragma unroll
        for (int nf = 0; nf < 4; ++nf)
          acc[mf][nf] = __builtin_amdgcn_mfma_f32_16x16x32_bf16(af[mf], bfr[nf], acc[mf][nf], 0, 0, 0);
    }
    __syncthreads();
  }

  const int lrow4 = lhi * 4;

  if (MODE == 1) {
    #pragma unroll
    for (int mf = 0; mf < 4; ++mf)
      #pragma unroll
      for (int r = 0; r < 4; ++r) {
        float bv = bias[o0 + wr*64 + mf*16 + lrow4 + r];
        #pragma unroll
        for (int nf = 0; nf < 4; ++nf)
          acc[mf][nf][r] = __expf(acc[mf][nf][r] + bv);
      }
    #pragma unroll
    for (int hg = 0; hg < 2; ++hg) {
      #pragma unroll
      for (int nf = 0; nf < 4; ++nf) {
        float s = 0.f;
        #pragma unroll
        for (int mh = 0; mh < 2; ++mh)
          #pragma unroll
          for (int r = 0; r < 4; ++r)
            s += acc[hg*2+mh][nf][r];
        s += __shfl_xor(s, 16);
        s += __shfl_xor(s, 32);
        float inv = 1.0f / s;
        #pragma unroll
        for (int mh = 0; mh < 2; ++mh)
          #pragma unroll
          for (int r = 0; r < 4; ++r)
            acc[hg*2+mh][nf][r] *= inv;
      }
    }
  }

  if (MODE == 2) {
    float* outf = (float*)outp;
    #pragma unroll
    for (int mf = 0; mf < 4; ++mf)
      #pragma unroll
      for (int r = 0; r < 4; ++r) {
        int orow = o0 + wr*64 + mf*16 + lrow4 + r;
        size_t base = ((size_t)n*256 + orow)*L + l0 + wc*64 + lcol;
        #pragma unroll
        for (int nf = 0; nf < 4; ++nf) {
          size_t gi = base + (size_t)nf*16;
          outf[gi] = acc[mf][nf][r] + xres[gi];
        }
      }
  } else {
    ushort* outb = (ushort*)outp;
    #pragma unroll
    for (int mf = 0; mf < 4; ++mf)
      #pragma unroll
      for (int r = 0; r < 4; ++r) {
        int orow = o0 + wr*64 + mf*16 + lrow4 + r;
        size_t base = ((size_t)orow*ors + (size_t)n*ons)*L + l0 + wc*64 + lcol;
        #pragma unroll
        for (int nf = 0; nf < 4; ++nf)
          outb[base + (size_t)nf*16] = f2bf(acc[mf][nf][r]);
      }
  }
}

// ---------------- M2 = Wp x ctx_norm^T, bf16 pre-swizzled per n ------
__global__ __launch_bounds__(256) void k_m2(const float* __restrict__ Wp,
                                            float* __restrict__ ws)
{
  __shared__ float cn[32][33];
  int t = threadIdx.x, bx = blockIdx.x;
  int n = bx >> 3, h = bx & 7;
  int nh = bx;
  #pragma unroll
  for (int jj = 0; jj < 4; ++jj){
    int i = jj*256 + t;
    int k = i >> 5, v = i & 31;
    cn[k][v] = ws[F_CTX + (size_t)nh*1024 + i] / ws[F_DENOM + nh*32 + k];
  }
  __syncthreads();
  int c = t;
  const float* wrow = Wp + (size_t)c*256 + h*32;
  float w[32];
  #pragma unroll
  for (int v = 0; v < 32; ++v) w[v] = wrow[v];
  float s[32];
  #pragma unroll
  for (int k = 0; k < 32; ++k){
    float a = 0.f;
    #pragma unroll
    for (int v = 0; v < 32; ++v) a = fmaf(w[v], cn[k][v], a);
    s[k] = a;
  }
  char* base = (char*)ws + B_M2 + (size_t)n*131072;
  int opl = c >> 7, rl = c & 127, kc = h >> 1;
  #pragma unroll
  for (int gg = 0; gg < 4; ++gg){
    int g = (h & 1)*4 + gg;
    uint4 u = make_uint4(pack2(s[gg*8+0], s[gg*8+1]), pack2(s[gg*8+2], s[gg*8+3]),
                         pack2(s[gg*8+4], s[gg*8+5]), pack2(s[gg*8+6], s[gg*8+7]));
    *(uint4*)(base + (size_t)((opl*4 + kc)*1024 + rl*8 + (g ^ swz(rl)))*16) = u;
  }
}

extern "C" void kernel_launch(void* const* d_in, const int* in_sizes, int n_in,
                              void* d_out, int out_size, void* d_ws, size_t ws_size,
                              hipStream_t stream)
{
  const float* q_in = (const float*)d_in[0];
  const float* kv   = (const float*)d_in[1];
  const float* Wq   = (const float*)d_in[2];
  const float* Wk   = (const float*)d_in[3];
  const float* Wv   = (const float*)d_in[4];
  const float* Wp   = (const float*)d_in[5];
  const float* qg   = (const float*)d_in[6];
  const float* qb   = (const float*)d_in[7];
  const float* kg   = (const float*)d_in[8];
  const float* kb   = (const float*)d_in[9];
  float* out = (float*)d_out;
  float* wsf = (float*)d_ws;
  char*  outa = (char*)d_out;
  ushort* qsm = (ushort*)((char*)d_ws + B_QSM);
  const float* biasf = (const float*)(outa + O_BIAS);

  k_init <<<dim3(268),  dim3(256), 0, stream>>>(wsf);
  k_stats<<<dim3(4096), dim3(256), 0, stream>>>(q_in, kv, wsf);
  k_wfold<<<dim3(3),    dim3(256), 0, stream>>>(Wk, Wv, Wq, wsf, qg, qb, kg, kb, outa);
  k_fkv  <<<dim3(576),  dim3(256), 0, stream>>>(outa + O_WF, kv, biasf, wsf);
  k_m2   <<<dim3(64),   dim3(256), 0, stream>>>(Wp, wsf);
  k_gemm<1><<<dim3(1152), dim3(256), 0, stream>>>(outa + O_WF + 262144, 0, q_in,
      biasf + 512, qsm, nullptr, 1, 256);
  k_gemm<2><<<dim3(1152), dim3(256), 0, stream>>>((char*)d_ws + B_M2, 131072, qsm,
      nullptr, out, q_in, 1, 256);
}